// Round 1
// baseline (1299.919 us; speedup 1.0000x reference)
//
#include <hip/hip_runtime.h>
#include <math.h>

#define SS 256
#define BB 4
#define HH 256
#define LE 2994
#define LEB (LE*BB)
#define SCALE 0.08838834764831845f  // 1/sqrt(128)

// ---------------- utility kernels ----------------

__global__ void k_zero(float* p) { p[0] = 0.f; }

__global__ void k_init_tables(int* __restrict__ grp, int* __restrict__ idxt) {
    int e = blockIdx.x * 256 + threadIdx.x;
    if (e >= LE) return;
    int g, pos;
    if (e < 78) {
        g = (int)((1.0f + sqrtf(8.0f * (float)e + 1.0f)) * 0.5f);
        while (g * (g - 1) / 2 > e) g--;
        while ((g + 1) * g / 2 <= e) g++;
        pos = e - g * (g - 1) / 2;
        idxt[e] = pos;                 // groups 1..12 attend nodes [0, g)
    } else {
        int r = e - 78;
        g = 13 + r / 12;
        pos = r % 12;
        idxt[e] = g - 12 + pos;        // groups >=13 attend nodes [g-12, g)
    }
    grp[e] = g;
}

// ---------------- generic fp32 GEMM: C[M,N] = A[M,K] @ W[N,K]^T + bias ----------------
// 64x64 tile, 16x16 threads, 4x4 per thread, K-tile 16.

__global__ __launch_bounds__(256) void k_gemm(
    const float* __restrict__ A, const float* __restrict__ W,
    const float* __restrict__ bias, float* __restrict__ C,
    int M, int N, int K, int relu)
{
    __shared__ __align__(16) float As[16][68];
    __shared__ __align__(16) float Ws[16][68];
    int tx = threadIdx.x, ty = threadIdx.y;
    int tid = ty * 16 + tx;
    int m0 = blockIdx.y * 64, n0 = blockIdx.x * 64;
    float acc[4][4] = {{0.f}};
    int r  = tid >> 2;
    int kk = (tid & 3) << 2;
    bool k4 = ((K & 3) == 0);
    for (int k0 = 0; k0 < K; k0 += 16) {
        float4 av = make_float4(0.f, 0.f, 0.f, 0.f);
        float4 wv = make_float4(0.f, 0.f, 0.f, 0.f);
        int gm = m0 + r, gk = k0 + kk;
        if (gm < M) {
            if (k4 && gk + 4 <= K) av = *(const float4*)(A + (size_t)gm * K + gk);
            else {
                float tv[4];
                for (int i = 0; i < 4; i++) tv[i] = (gk + i < K) ? A[(size_t)gm * K + gk + i] : 0.f;
                av = make_float4(tv[0], tv[1], tv[2], tv[3]);
            }
        }
        int gn = n0 + r;
        if (gn < N) {
            if (k4 && gk + 4 <= K) wv = *(const float4*)(W + (size_t)gn * K + gk);
            else {
                float tv[4];
                for (int i = 0; i < 4; i++) tv[i] = (gk + i < K) ? W[(size_t)gn * K + gk + i] : 0.f;
                wv = make_float4(tv[0], tv[1], tv[2], tv[3]);
            }
        }
        As[kk + 0][r] = av.x; As[kk + 1][r] = av.y; As[kk + 2][r] = av.z; As[kk + 3][r] = av.w;
        Ws[kk + 0][r] = wv.x; Ws[kk + 1][r] = wv.y; Ws[kk + 2][r] = wv.z; Ws[kk + 3][r] = wv.w;
        __syncthreads();
        #pragma unroll
        for (int k = 0; k < 16; k++) {
            float4 a4 = *(const float4*)&As[k][ty << 2];
            float4 b4 = *(const float4*)&Ws[k][tx << 2];
            float a[4] = {a4.x, a4.y, a4.z, a4.w};
            float b[4] = {b4.x, b4.y, b4.z, b4.w};
            #pragma unroll
            for (int i = 0; i < 4; i++)
                #pragma unroll
                for (int j = 0; j < 4; j++)
                    acc[i][j] = fmaf(a[i], b[j], acc[i][j]);
        }
        __syncthreads();
    }
    #pragma unroll
    for (int i = 0; i < 4; i++) {
        int gm = m0 + (ty << 2) + i;
        if (gm >= M) continue;
        #pragma unroll
        for (int j = 0; j < 4; j++) {
            int gn = n0 + (tx << 2) + j;
            if (gn >= N) continue;
            float v = acc[i][j] + bias[gn];
            if (relu) v = fmaxf(v, 0.f);
            C[(size_t)gm * N + gn] = v;
        }
    }
}

// ---------------- residual + LayerNorm (wave per row, 4 rows/block) ----------------
// mode 0: LN(x + delta[row]); mode 1: LN(x + delta[row%B]); mode 2: LN(x)

__global__ __launch_bounds__(256) void k_add_ln(
    const float* __restrict__ x, const float* __restrict__ delta,
    const float* __restrict__ g, const float* __restrict__ bta,
    float* __restrict__ out, int M, int mode)
{
    int row = blockIdx.x * 4 + (threadIdx.x >> 6);
    int t = threadIdx.x & 63;
    if (row >= M) return;
    float4 v = ((const float4*)(x + (size_t)row * HH))[t];
    if (mode == 0) {
        float4 d = ((const float4*)(delta + (size_t)row * HH))[t];
        v.x += d.x; v.y += d.y; v.z += d.z; v.w += d.w;
    } else if (mode == 1) {
        float4 d = ((const float4*)(delta + (size_t)(row & 3) * HH))[t];
        v.x += d.x; v.y += d.y; v.z += d.z; v.w += d.w;
    }
    float s = v.x + v.y + v.z + v.w;
    for (int o = 32; o; o >>= 1) s += __shfl_down(s, o);
    float mean = __shfl(s, 0) * (1.f / 256.f);
    float cx = v.x - mean, cy = v.y - mean, cz = v.z - mean, cw = v.w - mean;
    float q = cx * cx + cy * cy + cz * cz + cw * cw;
    for (int o = 32; o; o >>= 1) q += __shfl_down(q, o);
    float rstd = rsqrtf(__shfl(q, 0) * (1.f / 256.f) + 1e-5f);
    float4 gg = ((const float4*)g)[t];
    float4 bb = ((const float4*)bta)[t];
    float4 o4;
    o4.x = cx * rstd * gg.x + bb.x;
    o4.y = cy * rstd * gg.y + bb.y;
    o4.z = cz * rstd * gg.z + bb.z;
    o4.w = cw * rstd * gg.w + bb.w;
    ((float4*)(out + (size_t)row * HH))[t] = o4;
}

// ---------------- BatchNorm stats (per column over 1024 rows) ----------------

__global__ __launch_bounds__(256) void k_bn_stats(const float* __restrict__ x, float* __restrict__ mv) {
    int c = blockIdx.x, t = threadIdx.x;
    float s = 0.f, s2 = 0.f;
    for (int r = t; r < 1024; r += 256) {
        float v = x[(size_t)r * 256 + c];
        s += v; s2 += v * v;
    }
    __shared__ float rs[256], rs2[256];
    rs[t] = s; rs2[t] = s2; __syncthreads();
    for (int o = 128; o; o >>= 1) {
        if (t < o) { rs[t] += rs[t + o]; rs2[t] += rs2[t + o]; }
        __syncthreads();
    }
    if (t == 0) {
        float m = rs[0] * (1.f / 1024.f);
        float var = rs2[0] * (1.f / 1024.f) - m * m;
        mv[c] = m;
        mv[256 + c] = rsqrtf(var + 1e-5f);
    }
}

// ---------------- BN-normalize + SELU + positional encoding ----------------

__global__ __launch_bounds__(256) void k_bn_selu_pe(
    const float* __restrict__ x0, const float* __restrict__ mv,
    const float* __restrict__ g, const float* __restrict__ b,
    const int* __restrict__ atom_i, float* __restrict__ out)
{
    int row = blockIdx.x, t = threadIdx.x;
    float v = x0[(size_t)row * 256 + t];
    v = (v - mv[t]) * mv[256 + t] * g[t] + b[t];
    const float SC = 1.0507009873554805f, AL = 1.6732632423543772f;
    v = SC * (v > 0.f ? v : AL * expm1f(v));
    float pos = (float)atom_i[row];
    // SIN_F[k]=10000^{-2k/256} at t=2k; COS_F[k]=10000^{-(2k+1)/256} at t=2k+1 -> both 10000^{-t/256}
    float freq = expf(-(float)t * (9.210340371976184f / 256.f));
    float ang = pos * freq;
    float pe = (t & 1) ? cosf(ang) : sinf(ang);
    out[(size_t)row * 256 + t] = v + pe;
}

// ---------------- node causal self-attention (block per (q, b*2+h), 128 thr) ----------------

__global__ __launch_bounds__(128) void k_node_attn(
    const float* __restrict__ qkv, float* __restrict__ out)
{
    int q = blockIdx.x;
    int b = blockIdx.y >> 1, h = blockIdx.y & 1;
    int t = threadIdx.x;
    __shared__ float qv[128];
    __shared__ float sc[256];
    __shared__ float red[128];
    size_t rq = ((size_t)q * BB + b) * 768 + h * 128;
    qv[t] = qkv[rq + t];
    __syncthreads();
    for (int k = t; k < 256; k += 128) {
        float sv = -1e30f;
        if (k <= q) {
            const float* kp = qkv + ((size_t)k * BB + b) * 768 + 256 + h * 128;
            float acc = 0.f;
            for (int d = 0; d < 128; d++) acc = fmaf(qv[d], kp[d], acc);
            sv = acc * SCALE;
        }
        sc[k] = sv;
    }
    __syncthreads();
    red[t] = fmaxf(sc[t], sc[t + 128]);
    __syncthreads();
    for (int o = 64; o; o >>= 1) { if (t < o) red[t] = fmaxf(red[t], red[t + o]); __syncthreads(); }
    float m = red[0];
    __syncthreads();
    float e0 = expf(sc[t] - m), e1 = expf(sc[t + 128] - m);
    sc[t] = e0; sc[t + 128] = e1;
    red[t] = e0 + e1;
    __syncthreads();
    for (int o = 64; o; o >>= 1) { if (t < o) red[t] += red[t + o]; __syncthreads(); }
    float inv = 1.f / red[0];
    float acc = 0.f;
    const float* vp = qkv + (size_t)b * 768 + 512 + h * 128 + t;
    for (int k = 0; k <= q; k++) acc = fmaf(sc[k], vp[(size_t)k * BB * 768], acc);
    out[((size_t)q * BB + b) * 256 + h * 128 + t] = acc * inv;
}

// ---------------- edge group self-attention (block per (group, b), 256 thr = 2 heads) ----------------

__global__ __launch_bounds__(256) void k_edge_self_attn(
    const float* __restrict__ qkv, float* __restrict__ out)
{
    int g = blockIdx.x + 1;   // 1..255
    int b = blockIdx.y;
    int gs = min(g, 12);
    int base = (g <= 13) ? g * (g - 1) / 2 : 78 + (g - 13) * 12;
    int h = threadIdx.x >> 7;
    int t = threadIdx.x & 127;
    __shared__ float qs[2][12][128], ks[2][12][128], vs[2][12][128];
    __shared__ float ps[2][12][12];
    for (int i = 0; i < gs; i++) {
        size_t row = ((size_t)(base + i) * BB + b) * 768 + h * 128 + t;
        qs[h][i][t] = qkv[row];
        ks[h][i][t] = qkv[row + 256];
        vs[h][i][t] = qkv[row + 512];
    }
    __syncthreads();
    for (int p = t; p < gs * gs; p += 128) {
        int i = p / gs, j = p - i * gs;
        float acc = 0.f;
        for (int d = 0; d < 128; d++) acc = fmaf(qs[h][i][d], ks[h][j][d], acc);
        ps[h][i][j] = acc * SCALE;
    }
    __syncthreads();
    if (t < gs) {
        float m = -1e30f;
        for (int j = 0; j < gs; j++) m = fmaxf(m, ps[h][t][j]);
        float e[12]; float s = 0.f;
        for (int j = 0; j < gs; j++) { e[j] = expf(ps[h][t][j] - m); s += e[j]; }
        float inv = 1.f / s;
        for (int j = 0; j < gs; j++) ps[h][t][j] = e[j] * inv;
    }
    __syncthreads();
    for (int i = 0; i < gs; i++) {
        float acc = 0.f;
        for (int j = 0; j < gs; j++) acc = fmaf(ps[h][i][j], vs[h][j][t], acc);
        out[((size_t)(base + i) * BB + b) * 256 + h * 128 + t] = acc;
    }
}

// ---------------- edge 2-key cross-attention (block per (e,b), 128 thr = 2 heads x 64 lanes) ----------------

__global__ __launch_bounds__(128) void k_edge_cross_attn(
    const float* __restrict__ Q, const float* __restrict__ KV,
    const int* __restrict__ grp, float* __restrict__ out)
{
    int e = blockIdx.x, b = blockIdx.y;
    int h = threadIdx.x >> 6, l = threadIdx.x & 63;
    int g = grp[e];
    size_t qrow = ((size_t)e * BB + b) * 256 + h * 128;
    float qa = Q[qrow + l], qb = Q[qrow + 64 + l];
    size_t k0r = (size_t)b * 512 + h * 128;                    // mem slot 0 = z
    size_t k1r = ((size_t)(g + 1) * BB + b) * 512 + h * 128;   // mem slot grp+1 = node_emb[grp]
    float p0 = qa * KV[k0r + l] + qb * KV[k0r + 64 + l];
    float p1 = qa * KV[k1r + l] + qb * KV[k1r + 64 + l];
    for (int o = 32; o; o >>= 1) { p0 += __shfl_down(p0, o); p1 += __shfl_down(p1, o); }
    p0 = __shfl(p0, 0) * SCALE;
    p1 = __shfl(p1, 0) * SCALE;
    float m = fmaxf(p0, p1);
    float e0 = expf(p0 - m), e1 = expf(p1 - m);
    float inv = 1.f / (e0 + e1);
    e0 *= inv; e1 *= inv;
    out[qrow + l]      = e0 * KV[k0r + 256 + l]      + e1 * KV[k1r + 256 + l];
    out[qrow + 64 + l] = e0 * KV[k0r + 256 + 64 + l] + e1 * KV[k1r + 256 + 64 + l];
}

// ---------------- gathers ----------------

__global__ __launch_bounds__(256) void k_gather(
    const float* __restrict__ src, const int* __restrict__ idxt, float* __restrict__ dst)
{
    int r = blockIdx.x, t = threadIdx.x;   // r in [0, LEB)
    int e = r >> 2, b = r & 3;
    dst[(size_t)r * 256 + t] = src[((size_t)idxt[e] * 4 + b) * 256 + t];
}

__global__ __launch_bounds__(256) void k_build_mem(
    const float* __restrict__ z, const float* __restrict__ nemb, float* __restrict__ mem)
{
    int r = blockIdx.x, t = threadIdx.x;   // r in [0, 1028)
    int m = r >> 2, b = r & 3;
    mem[(size_t)r * 256 + t] = (m == 0) ? z[(size_t)b * 256 + t]
                                        : nemb[((size_t)(m - 1) * 4 + b) * 256 + t];
}

// ---------------- cross-entropy loss (wave per block, grid-strided rows) ----------------

__global__ __launch_bounds__(64) void k_ce(
    const float* __restrict__ emb, const float* __restrict__ w,
    const float* __restrict__ bias, const int* __restrict__ y,
    int M, int C, int ycols, int ycol, float invM, float* __restrict__ lossOut)
{
    int t = threadIdx.x;
    float local = 0.f;
    for (int r = blockIdx.x; r < M; r += gridDim.x) {
        float logit = -1e30f;
        if (t < C) {
            const float* wp = w + (size_t)t * 256;
            const float* xp = emb + (size_t)r * 256;
            float acc = bias[t];
            for (int d = 0; d < 256; d++) acc = fmaf(xp[d], wp[d], acc);
            logit = acc;
        }
        float m = logit;
        for (int o = 32; o; o >>= 1) m = fmaxf(m, __shfl_down(m, o));
        m = __shfl(m, 0);
        float e = (t < C) ? expf(logit - m) : 0.f;
        float s = e;
        for (int o = 32; o; o >>= 1) s += __shfl_down(s, o);
        s = __shfl(s, 0);
        int yy = y[(size_t)r * ycols + ycol];
        float ly = __shfl(logit, yy);
        if (t == 0) local += (m + logf(s)) - ly;
    }
    if (t == 0) atomicAdd(lossOut, local * invM);
}

// ---------------- host ----------------

extern "C" void kernel_launch(void* const* d_in, const int* in_sizes, int n_in,
                              void* d_out, int out_size, void* d_ws, size_t ws_size,
                              hipStream_t stream)
{
    (void)in_sizes; (void)n_in; (void)out_size; (void)ws_size;
    const float* z        = (const float*)d_in[0];
    const int*   atom_i   = (const int*)d_in[1];
    const float* atom_x   = (const float*)d_in[2];
    const int*   atom_y   = (const int*)d_in[3];
    const int*   bond_y   = (const int*)d_in[4];
    const float* Wp       = (const float*)d_in[5];
    const float* bp       = (const float*)d_in[6];
    const float* bn_g     = (const float*)d_in[7];
    const float* bn_b     = (const float*)d_in[8];
    const float* nd_qkv_w = (const float*)d_in[9];
    const float* nd_qkv_b = (const float*)d_in[10];
    const float* nd_so_w  = (const float*)d_in[11];
    const float* nd_so_b  = (const float*)d_in[12];
    const float* nd_cqkv_w= (const float*)d_in[13];
    const float* nd_cqkv_b= (const float*)d_in[14];
    const float* nd_co_w  = (const float*)d_in[15];
    const float* nd_co_b  = (const float*)d_in[16];
    const float* nd_ff1_w = (const float*)d_in[17];
    const float* nd_ff1_b = (const float*)d_in[18];
    const float* nd_ff2_w = (const float*)d_in[19];
    const float* nd_ff2_b = (const float*)d_in[20];
    const float* nd_ln_g  = (const float*)d_in[21];
    const float* nd_ln_b  = (const float*)d_in[22];
    const float* nd_fn_g  = (const float*)d_in[23];
    const float* nd_fn_b  = (const float*)d_in[24];
    const float* ed_qkv_w = (const float*)d_in[25];
    const float* ed_qkv_b = (const float*)d_in[26];
    const float* ed_so_w  = (const float*)d_in[27];
    const float* ed_so_b  = (const float*)d_in[28];
    const float* ed_cqkv_w= (const float*)d_in[29];
    const float* ed_cqkv_b= (const float*)d_in[30];
    const float* ed_co_w  = (const float*)d_in[31];
    const float* ed_co_b  = (const float*)d_in[32];
    const float* ed_ff1_w = (const float*)d_in[33];
    const float* ed_ff1_b = (const float*)d_in[34];
    const float* ed_ff2_w = (const float*)d_in[35];
    const float* ed_ff2_b = (const float*)d_in[36];
    const float* ed_ln_g  = (const float*)d_in[37];
    const float* ed_ln_b  = (const float*)d_in[38];
    const float* ed_fn_g  = (const float*)d_in[39];
    const float* ed_fn_b  = (const float*)d_in[40];
    const float* nc0_w = (const float*)d_in[41]; const float* nc0_b = (const float*)d_in[42];
    const float* nc1_w = (const float*)d_in[43]; const float* nc1_b = (const float*)d_in[44];
    const float* nc2_w = (const float*)d_in[45]; const float* nc2_b = (const float*)d_in[46];
    const float* ec0_w = (const float*)d_in[47]; const float* ec0_b = (const float*)d_in[48];
    const float* ec1_w = (const float*)d_in[49]; const float* ec1_b = (const float*)d_in[50];

    float* out = (float*)d_out;

    char* wsb = (char*)d_ws;
    size_t off = 0;
    auto alloc = [&](size_t nfloats) -> float* {
        float* p = (float*)(wsb + off);
        off += ((nfloats * 4 + 255) / 256) * 256;
        return p;
    };
    float* x0   = alloc(1024 * 256);
    float* tgt  = alloc(1024 * 256);
    float* nqkv = alloc(1024 * 768);
    float* t1   = alloc(1024 * 256);
    float* t2   = alloc(1024 * 256);
    float* nemb = alloc(1024 * 256);
    float* bnmv = alloc(512);
    float* crT  = alloc(4 * 256);
    float* crO  = alloc(4 * 256);
    float* memb = alloc(1028 * 256);
    float* KV   = alloc(1028 * 512);
    float* etgt = alloc((size_t)LEB * 256);
    float* eqkv = alloc((size_t)LEB * 768);
    float* et1  = alloc((size_t)LEB * 256);
    float* et2  = alloc((size_t)LEB * 256);
    int* grp  = (int*)(wsb + off); off += ((LE * 4 + 255) / 256) * 256;
    int* idxt = (int*)(wsb + off); off += ((LE * 4 + 255) / 256) * 256;

    dim3 blk(16, 16);
    auto gemm = [&](const float* A, const float* W, const float* bi, float* C,
                    int M, int N, int K, int relu) {
        dim3 grid((N + 63) / 64, (M + 63) / 64);
        k_gemm<<<grid, blk, 0, stream>>>(A, W, bi, C, M, N, K, relu);
    };

    k_zero<<<1, 1, 0, stream>>>(out);
    k_init_tables<<<12, 256, 0, stream>>>(grp, idxt);

    // node input: projection + BN(training stats) + SELU + positional encoding
    gemm(atom_x, Wp, bp, x0, 1024, 256, 54, 0);
    k_bn_stats<<<256, 256, 0, stream>>>(x0, bnmv);
    k_bn_selu_pe<<<1024, 256, 0, stream>>>(x0, bnmv, bn_g, bn_b, atom_i, tgt);

    // node decoder: 2 layers
    for (int l = 0; l < 2; l++) {
        gemm(tgt, nd_qkv_w + (size_t)l * 768 * 256, nd_qkv_b + l * 768, nqkv, 1024, 768, 256, 0);
        k_node_attn<<<dim3(256, 8), 128, 0, stream>>>(nqkv, t1);
        gemm(t1, nd_so_w + (size_t)l * 65536, nd_so_b + l * 256, t2, 1024, 256, 256, 0);
        k_add_ln<<<256, 256, 0, stream>>>(tgt, t2, nd_ln_g + (l * 3 + 0) * 256, nd_ln_b + (l * 3 + 0) * 256, tgt, 1024, 0);
        // cross-attn over length-1 memory == broadcast of (z@wv.T+bv)@o_w.T+o_b
        gemm(z,   nd_cqkv_w + (size_t)l * 768 * 256 + 512 * 256, nd_cqkv_b + l * 768 + 512, crT, 4, 256, 256, 0);
        gemm(crT, nd_co_w + (size_t)l * 65536, nd_co_b + l * 256, crO, 4, 256, 256, 0);
        k_add_ln<<<256, 256, 0, stream>>>(tgt, crO, nd_ln_g + (l * 3 + 1) * 256, nd_ln_b + (l * 3 + 1) * 256, tgt, 1024, 1);
        gemm(tgt, nd_ff1_w + (size_t)l * 65536, nd_ff1_b + l * 256, t1, 1024, 256, 256, 1);
        gemm(t1,  nd_ff2_w + (size_t)l * 65536, nd_ff2_b + l * 256, t2, 1024, 256, 256, 0);
        k_add_ln<<<256, 256, 0, stream>>>(tgt, t2, nd_ln_g + (l * 3 + 2) * 256, nd_ln_b + (l * 3 + 2) * 256, tgt, 1024, 0);
    }
    k_add_ln<<<256, 256, 0, stream>>>(tgt, nullptr, nd_fn_g, nd_fn_b, nemb, 1024, 2);

    // node losses
    k_ce<<<256, 64, 0, stream>>>(nemb, nc0_w, nc0_b, atom_y, 1024, 40, 3, 0, 1.f / 1024.f, out);
    k_ce<<<256, 64, 0, stream>>>(nemb, nc1_w, nc1_b, atom_y, 1024,  8, 3, 1, 1.f / 1024.f, out);
    k_ce<<<256, 64, 0, stream>>>(nemb, nc2_w, nc2_b, atom_y, 1024,  6, 3, 2, 1.f / 1024.f, out);

    // edge path
    k_gather<<<LEB, 256, 0, stream>>>(nemb, idxt, etgt);
    k_build_mem<<<1028, 256, 0, stream>>>(z, nemb, memb);
    gemm(memb, ed_cqkv_w + 256 * 256, ed_cqkv_b + 256, KV, 1028, 512, 256, 0);  // K,V of edge_mem

    gemm(etgt, ed_qkv_w, ed_qkv_b, eqkv, LEB, 768, 256, 0);
    k_edge_self_attn<<<dim3(255, 4), 256, 0, stream>>>(eqkv, et1);
    gemm(et1, ed_so_w, ed_so_b, et2, LEB, 256, 256, 0);
    k_add_ln<<<LEB / 4, 256, 0, stream>>>(etgt, et2, ed_ln_g + 0, ed_ln_b + 0, etgt, LEB, 0);

    gemm(etgt, ed_cqkv_w, ed_cqkv_b, eqkv, LEB, 256, 256, 0);  // q projection (reuse eqkv)
    k_edge_cross_attn<<<dim3(LE, 4), 128, 0, stream>>>(eqkv, KV, grp, et1);
    gemm(et1, ed_co_w, ed_co_b, et2, LEB, 256, 256, 0);
    k_add_ln<<<LEB / 4, 256, 0, stream>>>(etgt, et2, ed_ln_g + 256, ed_ln_b + 256, etgt, LEB, 0);

    gemm(etgt, ed_ff1_w, ed_ff1_b, et1, LEB, 256, 256, 1);
    gemm(et1,  ed_ff2_w, ed_ff2_b, et2, LEB, 256, 256, 0);
    k_add_ln<<<LEB / 4, 256, 0, stream>>>(etgt, et2, ed_ln_g + 512, ed_ln_b + 512, etgt, LEB, 0);
    k_add_ln<<<LEB / 4, 256, 0, stream>>>(etgt, nullptr, ed_fn_g, ed_fn_b, etgt, LEB, 2);

    // edge losses
    k_ce<<<256, 64, 0, stream>>>(etgt, ec0_w, ec0_b, bond_y, LEB, 5, 2, 0, 1.f / (float)LEB, out);
    k_ce<<<256, 64, 0, stream>>>(etgt, ec1_w, ec1_b, bond_y, LEB, 4, 2, 1, 1.f / (float)LEB, out);
}

// Round 2
// 919.100 us; speedup vs baseline: 1.4143x; 1.4143x over previous
//
#include <hip/hip_runtime.h>
#include <math.h>

#define SS 256
#define BB 4
#define HH 256
#define LE 2994
#define LEB (LE*BB)
#define SCALE 0.08838834764831845f  // 1/sqrt(128)

// ---------------- utility kernels ----------------

__global__ void k_zero(float* p, int n) {
    int i = blockIdx.x * 256 + threadIdx.x;
    if (i < n) p[i] = 0.f;
}

__global__ void k_init_tables(int* __restrict__ grp, int* __restrict__ idxt) {
    int e = blockIdx.x * 256 + threadIdx.x;
    if (e >= LE) return;
    int g, pos;
    if (e < 78) {
        g = (int)((1.0f + sqrtf(8.0f * (float)e + 1.0f)) * 0.5f);
        while (g * (g - 1) / 2 > e) g--;
        while ((g + 1) * g / 2 <= e) g++;
        pos = e - g * (g - 1) / 2;
        idxt[e] = pos;                 // groups 1..12 attend nodes [0, g)
    } else {
        int r = e - 78;
        g = 13 + r / 12;
        pos = r % 12;
        idxt[e] = g - 12 + pos;        // groups >=13 attend nodes [g-12, g)
    }
    grp[e] = g;
}

// ---------------- generic fp32 GEMM: C[M,N] = A[M,K] @ W[N,K]^T + bias ----------------
// 64x64 tile, 16x16 threads, 4x4 per thread, K-tile 16.

__global__ __launch_bounds__(256) void k_gemm(
    const float* __restrict__ A, const float* __restrict__ W,
    const float* __restrict__ bias, float* __restrict__ C,
    int M, int N, int K, int relu)
{
    __shared__ __align__(16) float As[16][68];
    __shared__ __align__(16) float Ws[16][68];
    int tx = threadIdx.x, ty = threadIdx.y;
    int tid = ty * 16 + tx;
    int m0 = blockIdx.y * 64, n0 = blockIdx.x * 64;
    float acc[4][4] = {{0.f}};
    int r  = tid >> 2;
    int kk = (tid & 3) << 2;
    bool k4 = ((K & 3) == 0);
    for (int k0 = 0; k0 < K; k0 += 16) {
        float4 av = make_float4(0.f, 0.f, 0.f, 0.f);
        float4 wv = make_float4(0.f, 0.f, 0.f, 0.f);
        int gm = m0 + r, gk = k0 + kk;
        if (gm < M) {
            if (k4 && gk + 4 <= K) av = *(const float4*)(A + (size_t)gm * K + gk);
            else {
                float tv[4];
                for (int i = 0; i < 4; i++) tv[i] = (gk + i < K) ? A[(size_t)gm * K + gk + i] : 0.f;
                av = make_float4(tv[0], tv[1], tv[2], tv[3]);
            }
        }
        int gn = n0 + r;
        if (gn < N) {
            if (k4 && gk + 4 <= K) wv = *(const float4*)(W + (size_t)gn * K + gk);
            else {
                float tv[4];
                for (int i = 0; i < 4; i++) tv[i] = (gk + i < K) ? W[(size_t)gn * K + gk + i] : 0.f;
                wv = make_float4(tv[0], tv[1], tv[2], tv[3]);
            }
        }
        As[kk + 0][r] = av.x; As[kk + 1][r] = av.y; As[kk + 2][r] = av.z; As[kk + 3][r] = av.w;
        Ws[kk + 0][r] = wv.x; Ws[kk + 1][r] = wv.y; Ws[kk + 2][r] = wv.z; Ws[kk + 3][r] = wv.w;
        __syncthreads();
        #pragma unroll
        for (int k = 0; k < 16; k++) {
            float4 a4 = *(const float4*)&As[k][ty << 2];
            float4 b4 = *(const float4*)&Ws[k][tx << 2];
            float a[4] = {a4.x, a4.y, a4.z, a4.w};
            float b[4] = {b4.x, b4.y, b4.z, b4.w};
            #pragma unroll
            for (int i = 0; i < 4; i++)
                #pragma unroll
                for (int j = 0; j < 4; j++)
                    acc[i][j] = fmaf(a[i], b[j], acc[i][j]);
        }
        __syncthreads();
    }
    #pragma unroll
    for (int i = 0; i < 4; i++) {
        int gm = m0 + (ty << 2) + i;
        if (gm >= M) continue;
        #pragma unroll
        for (int j = 0; j < 4; j++) {
            int gn = n0 + (tx << 2) + j;
            if (gn >= N) continue;
            float v = acc[i][j] + bias[gn];
            if (relu) v = fmaxf(v, 0.f);
            C[(size_t)gm * N + gn] = v;
        }
    }
}

// ---------------- residual + LayerNorm (wave per row, 4 rows/block) ----------------
// mode 0: LN(x + delta[row]); mode 1: LN(x + delta[row%B]); mode 2: LN(x)

__global__ __launch_bounds__(256) void k_add_ln(
    const float* __restrict__ x, const float* __restrict__ delta,
    const float* __restrict__ g, const float* __restrict__ bta,
    float* __restrict__ out, int M, int mode)
{
    int row = blockIdx.x * 4 + (threadIdx.x >> 6);
    int t = threadIdx.x & 63;
    if (row >= M) return;
    float4 v = ((const float4*)(x + (size_t)row * HH))[t];
    if (mode == 0) {
        float4 d = ((const float4*)(delta + (size_t)row * HH))[t];
        v.x += d.x; v.y += d.y; v.z += d.z; v.w += d.w;
    } else if (mode == 1) {
        float4 d = ((const float4*)(delta + (size_t)(row & 3) * HH))[t];
        v.x += d.x; v.y += d.y; v.z += d.z; v.w += d.w;
    }
    float s = v.x + v.y + v.z + v.w;
    for (int o = 32; o; o >>= 1) s += __shfl_down(s, o);
    float mean = __shfl(s, 0) * (1.f / 256.f);
    float cx = v.x - mean, cy = v.y - mean, cz = v.z - mean, cw = v.w - mean;
    float q = cx * cx + cy * cy + cz * cz + cw * cw;
    for (int o = 32; o; o >>= 1) q += __shfl_down(q, o);
    float rstd = rsqrtf(__shfl(q, 0) * (1.f / 256.f) + 1e-5f);
    float4 gg = ((const float4*)g)[t];
    float4 bb = ((const float4*)bta)[t];
    float4 o4;
    o4.x = cx * rstd * gg.x + bb.x;
    o4.y = cy * rstd * gg.y + bb.y;
    o4.z = cz * rstd * gg.z + bb.z;
    o4.w = cw * rstd * gg.w + bb.w;
    ((float4*)(out + (size_t)row * HH))[t] = o4;
}

// ---------------- BatchNorm partial sums (row-coalesced, atomics per column) ----------------

__global__ __launch_bounds__(256) void k_bn_part(const float* __restrict__ x, float* __restrict__ sums) {
    int t = threadIdx.x;
    int r0 = blockIdx.x * 16;
    float s = 0.f, s2 = 0.f;
    for (int r = r0; r < r0 + 16; r++) {
        float v = x[(size_t)r * 256 + t];
        s += v; s2 += v * v;
    }
    atomicAdd(&sums[t], s);
    atomicAdd(&sums[256 + t], s2);
}

// ---------------- BN-finalize + SELU + positional encoding ----------------

__global__ __launch_bounds__(256) void k_bn_selu_pe(
    const float* __restrict__ x0, const float* __restrict__ sums,
    const float* __restrict__ g, const float* __restrict__ b,
    const int* __restrict__ atom_i, float* __restrict__ out)
{
    int row = blockIdx.x, t = threadIdx.x;
    float m = sums[t] * (1.f / 1024.f);
    float var = sums[256 + t] * (1.f / 1024.f) - m * m;
    float rstd = rsqrtf(var + 1e-5f);
    float v = x0[(size_t)row * 256 + t];
    v = (v - m) * rstd * g[t] + b[t];
    const float SC = 1.0507009873554805f, AL = 1.6732632423543772f;
    v = SC * (v > 0.f ? v : AL * expm1f(v));
    float pos = (float)atom_i[row];
    float freq = expf(-(float)t * (9.210340371976184f / 256.f));
    float ang = pos * freq;
    float pe = (t & 1) ? cosf(ang) : sinf(ang);
    out[(size_t)row * 256 + t] = v + pe;
}

// ---------------- node causal self-attention (block per (q, b*2+h), 128 thr) ----------------

__global__ __launch_bounds__(128) void k_node_attn(
    const float* __restrict__ qkv, float* __restrict__ out)
{
    int q = blockIdx.x;
    int b = blockIdx.y >> 1, h = blockIdx.y & 1;
    int t = threadIdx.x;
    __shared__ float qv[128];
    __shared__ float sc[256];
    __shared__ float red[128];
    size_t rq = ((size_t)q * BB + b) * 768 + h * 128;
    qv[t] = qkv[rq + t];
    __syncthreads();
    for (int k = t; k < 256; k += 128) {
        float sv = -1e30f;
        if (k <= q) {
            const float* kp = qkv + ((size_t)k * BB + b) * 768 + 256 + h * 128;
            float acc = 0.f;
            for (int d = 0; d < 128; d++) acc = fmaf(qv[d], kp[d], acc);
            sv = acc * SCALE;
        }
        sc[k] = sv;
    }
    __syncthreads();
    red[t] = fmaxf(sc[t], sc[t + 128]);
    __syncthreads();
    for (int o = 64; o; o >>= 1) { if (t < o) red[t] = fmaxf(red[t], red[t + o]); __syncthreads(); }
    float m = red[0];
    __syncthreads();
    float e0 = expf(sc[t] - m), e1 = expf(sc[t + 128] - m);
    sc[t] = e0; sc[t + 128] = e1;
    red[t] = e0 + e1;
    __syncthreads();
    for (int o = 64; o; o >>= 1) { if (t < o) red[t] += red[t + o]; __syncthreads(); }
    float inv = 1.f / red[0];
    float acc = 0.f;
    const float* vp = qkv + (size_t)b * 768 + 512 + h * 128 + t;
    for (int k = 0; k <= q; k++) acc = fmaf(sc[k], vp[(size_t)k * BB * 768], acc);
    out[((size_t)q * BB + b) * 256 + h * 128 + t] = acc * inv;
}

// ---------------- edge group self-attention (block per (group, b), 256 thr = 2 heads) ----------------

__global__ __launch_bounds__(256) void k_edge_self_attn(
    const float* __restrict__ qkv, float* __restrict__ out)
{
    int g = blockIdx.x + 1;   // 1..255
    int b = blockIdx.y;
    int gs = min(g, 12);
    int base = (g <= 13) ? g * (g - 1) / 2 : 78 + (g - 13) * 12;
    int h = threadIdx.x >> 7;
    int t = threadIdx.x & 127;
    __shared__ float qs[2][12][128], ks[2][12][128], vs[2][12][128];
    __shared__ float ps[2][12][12];
    for (int i = 0; i < gs; i++) {
        size_t row = ((size_t)(base + i) * BB + b) * 768 + h * 128 + t;
        qs[h][i][t] = qkv[row];
        ks[h][i][t] = qkv[row + 256];
        vs[h][i][t] = qkv[row + 512];
    }
    __syncthreads();
    for (int p = t; p < gs * gs; p += 128) {
        int i = p / gs, j = p - i * gs;
        float acc = 0.f;
        for (int d = 0; d < 128; d++) acc = fmaf(qs[h][i][d], ks[h][j][d], acc);
        ps[h][i][j] = acc * SCALE;
    }
    __syncthreads();
    if (t < gs) {
        float m = -1e30f;
        for (int j = 0; j < gs; j++) m = fmaxf(m, ps[h][t][j]);
        float e[12]; float s = 0.f;
        for (int j = 0; j < gs; j++) { e[j] = expf(ps[h][t][j] - m); s += e[j]; }
        float inv = 1.f / s;
        for (int j = 0; j < gs; j++) ps[h][t][j] = e[j] * inv;
    }
    __syncthreads();
    for (int i = 0; i < gs; i++) {
        float acc = 0.f;
        for (int j = 0; j < gs; j++) acc = fmaf(ps[h][i][j], vs[h][j][t], acc);
        out[((size_t)(base + i) * BB + b) * 256 + h * 128 + t] = acc;
    }
}

// ---------------- edge 2-key cross-attention (block per (e,b), 128 thr = 2 heads x 64 lanes) ----------------

__global__ __launch_bounds__(128) void k_edge_cross_attn(
    const float* __restrict__ Q, const float* __restrict__ KV,
    const int* __restrict__ grp, float* __restrict__ out)
{
    int e = blockIdx.x, b = blockIdx.y;
    int h = threadIdx.x >> 6, l = threadIdx.x & 63;
    int g = grp[e];
    size_t qrow = ((size_t)e * BB + b) * 256 + h * 128;
    float qa = Q[qrow + l], qb = Q[qrow + 64 + l];
    size_t k0r = (size_t)b * 512 + h * 128;                    // mem slot 0 = z
    size_t k1r = ((size_t)(g + 1) * BB + b) * 512 + h * 128;   // mem slot grp+1 = node_emb[grp]
    float p0 = qa * KV[k0r + l] + qb * KV[k0r + 64 + l];
    float p1 = qa * KV[k1r + l] + qb * KV[k1r + 64 + l];
    for (int o = 32; o; o >>= 1) { p0 += __shfl_down(p0, o); p1 += __shfl_down(p1, o); }
    p0 = __shfl(p0, 0) * SCALE;
    p1 = __shfl(p1, 0) * SCALE;
    float m = fmaxf(p0, p1);
    float e0 = expf(p0 - m), e1 = expf(p1 - m);
    float inv = 1.f / (e0 + e1);
    e0 *= inv; e1 *= inv;
    out[qrow + l]      = e0 * KV[k0r + 256 + l]      + e1 * KV[k1r + 256 + l];
    out[qrow + 64 + l] = e0 * KV[k0r + 256 + 64 + l] + e1 * KV[k1r + 256 + 64 + l];
}

// ---------------- gathers ----------------

__global__ __launch_bounds__(256) void k_gather(
    const float* __restrict__ src, const int* __restrict__ idxt, float* __restrict__ dst)
{
    int r = blockIdx.x, t = threadIdx.x;   // r in [0, LEB)
    int e = r >> 2, b = r & 3;
    dst[(size_t)r * 256 + t] = src[((size_t)idxt[e] * 4 + b) * 256 + t];
}

__global__ __launch_bounds__(256) void k_build_mem(
    const float* __restrict__ z, const float* __restrict__ nemb, float* __restrict__ mem)
{
    int r = blockIdx.x, t = threadIdx.x;   // r in [0, 1028)
    int m = r >> 2, b = r & 3;
    mem[(size_t)r * 256 + t] = (m == 0) ? z[(size_t)b * 256 + t]
                                        : nemb[((size_t)(m - 1) * 4 + b) * 256 + t];
}

// ---------------- fused cross-entropy: wave per row, lanes over d=256 ----------------
// Node: 3 heads (40, 8, 6 classes).  Edge: 2 heads (5, 4 classes).

__global__ __launch_bounds__(256) void k_ce_node(
    const float* __restrict__ emb,
    const float* __restrict__ w0, const float* __restrict__ b0,
    const float* __restrict__ w1, const float* __restrict__ b1,
    const float* __restrict__ w2, const float* __restrict__ b2,
    const int* __restrict__ y, int M, float invM, float* __restrict__ lossOut)
{
    int wave = threadIdx.x >> 6, lane = threadIdx.x & 63;
    int wid = blockIdx.x * 4 + wave;
    float local = 0.f;
    for (int r = wid; r < M; r += gridDim.x * 4) {
        float4 x = ((const float4*)(emb + (size_t)r * 256))[lane];
        float acc[54];
        #pragma unroll
        for (int c = 0; c < 40; c++) {
            float4 wv = ((const float4*)(w0 + (size_t)c * 256))[lane];
            acc[c] = x.x * wv.x + x.y * wv.y + x.z * wv.z + x.w * wv.w;
        }
        #pragma unroll
        for (int c = 0; c < 8; c++) {
            float4 wv = ((const float4*)(w1 + (size_t)c * 256))[lane];
            acc[40 + c] = x.x * wv.x + x.y * wv.y + x.z * wv.z + x.w * wv.w;
        }
        #pragma unroll
        for (int c = 0; c < 6; c++) {
            float4 wv = ((const float4*)(w2 + (size_t)c * 256))[lane];
            acc[48 + c] = x.x * wv.x + x.y * wv.y + x.z * wv.z + x.w * wv.w;
        }
        #pragma unroll
        for (int c = 0; c < 54; c++)
            for (int o = 32; o; o >>= 1) acc[c] += __shfl_down(acc[c], o);
        if (lane == 0) {
            int y0 = y[(size_t)r * 3 + 0], y1 = y[(size_t)r * 3 + 1], y2 = y[(size_t)r * 3 + 2];
            float m0 = -1e30f, m1 = -1e30f, m2 = -1e30f;
            float lg[54];
            for (int c = 0; c < 40; c++) { lg[c] = acc[c] + b0[c]; m0 = fmaxf(m0, lg[c]); }
            for (int c = 0; c < 8; c++)  { lg[40 + c] = acc[40 + c] + b1[c]; m1 = fmaxf(m1, lg[40 + c]); }
            for (int c = 0; c < 6; c++)  { lg[48 + c] = acc[48 + c] + b2[c]; m2 = fmaxf(m2, lg[48 + c]); }
            float s0 = 0.f, s1 = 0.f, s2 = 0.f;
            for (int c = 0; c < 40; c++) s0 += expf(lg[c] - m0);
            for (int c = 0; c < 8; c++)  s1 += expf(lg[40 + c] - m1);
            for (int c = 0; c < 6; c++)  s2 += expf(lg[48 + c] - m2);
            local += (m0 + logf(s0) - lg[y0]) + (m1 + logf(s1) - lg[40 + y1]) + (m2 + logf(s2) - lg[48 + y2]);
        }
    }
    __shared__ float ls[4];
    if (lane == 0) ls[wave] = local;
    __syncthreads();
    if (threadIdx.x == 0)
        atomicAdd(lossOut, (ls[0] + ls[1] + ls[2] + ls[3]) * invM);
}

__global__ __launch_bounds__(256) void k_ce_edge(
    const float* __restrict__ emb,
    const float* __restrict__ w0, const float* __restrict__ b0,
    const float* __restrict__ w1, const float* __restrict__ b1,
    const int* __restrict__ y, int M, float invM, float* __restrict__ lossOut)
{
    int wave = threadIdx.x >> 6, lane = threadIdx.x & 63;
    int wid = blockIdx.x * 4 + wave;
    float local = 0.f;
    for (int r = wid; r < M; r += gridDim.x * 4) {
        float4 x = ((const float4*)(emb + (size_t)r * 256))[lane];
        float acc[9];
        #pragma unroll
        for (int c = 0; c < 5; c++) {
            float4 wv = ((const float4*)(w0 + (size_t)c * 256))[lane];
            acc[c] = x.x * wv.x + x.y * wv.y + x.z * wv.z + x.w * wv.w;
        }
        #pragma unroll
        for (int c = 0; c < 4; c++) {
            float4 wv = ((const float4*)(w1 + (size_t)c * 256))[lane];
            acc[5 + c] = x.x * wv.x + x.y * wv.y + x.z * wv.z + x.w * wv.w;
        }
        #pragma unroll
        for (int c = 0; c < 9; c++)
            for (int o = 32; o; o >>= 1) acc[c] += __shfl_down(acc[c], o);
        if (lane == 0) {
            int y0 = y[(size_t)r * 2 + 0], y1 = y[(size_t)r * 2 + 1];
            float lg[9];
            float m0 = -1e30f, m1 = -1e30f;
            for (int c = 0; c < 5; c++) { lg[c] = acc[c] + b0[c]; m0 = fmaxf(m0, lg[c]); }
            for (int c = 0; c < 4; c++) { lg[5 + c] = acc[5 + c] + b1[c]; m1 = fmaxf(m1, lg[5 + c]); }
            float s0 = 0.f, s1 = 0.f;
            for (int c = 0; c < 5; c++) s0 += expf(lg[c] - m0);
            for (int c = 0; c < 4; c++) s1 += expf(lg[5 + c] - m1);
            local += (m0 + logf(s0) - lg[y0]) + (m1 + logf(s1) - lg[5 + y1]);
        }
    }
    __shared__ float ls[4];
    if (lane == 0) ls[wave] = local;
    __syncthreads();
    if (threadIdx.x == 0)
        atomicAdd(lossOut, (ls[0] + ls[1] + ls[2] + ls[3]) * invM);
}

// ---------------- host ----------------

extern "C" void kernel_launch(void* const* d_in, const int* in_sizes, int n_in,
                              void* d_out, int out_size, void* d_ws, size_t ws_size,
                              hipStream_t stream)
{
    (void)in_sizes; (void)n_in; (void)out_size; (void)ws_size;
    const float* z        = (const float*)d_in[0];
    const int*   atom_i   = (const int*)d_in[1];
    const float* atom_x   = (const float*)d_in[2];
    const int*   atom_y   = (const int*)d_in[3];
    const int*   bond_y   = (const int*)d_in[4];
    const float* Wp       = (const float*)d_in[5];
    const float* bp       = (const float*)d_in[6];
    const float* bn_g     = (const float*)d_in[7];
    const float* bn_b     = (const float*)d_in[8];
    const float* nd_qkv_w = (const float*)d_in[9];
    const float* nd_qkv_b = (const float*)d_in[10];
    const float* nd_so_w  = (const float*)d_in[11];
    const float* nd_so_b  = (const float*)d_in[12];
    const float* nd_cqkv_w= (const float*)d_in[13];
    const float* nd_cqkv_b= (const float*)d_in[14];
    const float* nd_co_w  = (const float*)d_in[15];
    const float* nd_co_b  = (const float*)d_in[16];
    const float* nd_ff1_w = (const float*)d_in[17];
    const float* nd_ff1_b = (const float*)d_in[18];
    const float* nd_ff2_w = (const float*)d_in[19];
    const float* nd_ff2_b = (const float*)d_in[20];
    const float* nd_ln_g  = (const float*)d_in[21];
    const float* nd_ln_b  = (const float*)d_in[22];
    const float* nd_fn_g  = (const float*)d_in[23];
    const float* nd_fn_b  = (const float*)d_in[24];
    const float* ed_qkv_w = (const float*)d_in[25];
    const float* ed_qkv_b = (const float*)d_in[26];
    const float* ed_so_w  = (const float*)d_in[27];
    const float* ed_so_b  = (const float*)d_in[28];
    const float* ed_cqkv_w= (const float*)d_in[29];
    const float* ed_cqkv_b= (const float*)d_in[30];
    const float* ed_co_w  = (const float*)d_in[31];
    const float* ed_co_b  = (const float*)d_in[32];
    const float* ed_ff1_w = (const float*)d_in[33];
    const float* ed_ff1_b = (const float*)d_in[34];
    const float* ed_ff2_w = (const float*)d_in[35];
    const float* ed_ff2_b = (const float*)d_in[36];
    const float* ed_ln_g  = (const float*)d_in[37];
    const float* ed_ln_b  = (const float*)d_in[38];
    const float* ed_fn_g  = (const float*)d_in[39];
    const float* ed_fn_b  = (const float*)d_in[40];
    const float* nc0_w = (const float*)d_in[41]; const float* nc0_b = (const float*)d_in[42];
    const float* nc1_w = (const float*)d_in[43]; const float* nc1_b = (const float*)d_in[44];
    const float* nc2_w = (const float*)d_in[45]; const float* nc2_b = (const float*)d_in[46];
    const float* ec0_w = (const float*)d_in[47]; const float* ec0_b = (const float*)d_in[48];
    const float* ec1_w = (const float*)d_in[49]; const float* ec1_b = (const float*)d_in[50];

    float* out = (float*)d_out;

    char* wsb = (char*)d_ws;
    size_t off = 0;
    auto alloc = [&](size_t nfloats) -> float* {
        float* p = (float*)(wsb + off);
        off += ((nfloats * 4 + 255) / 256) * 256;
        return p;
    };
    float* x0   = alloc(1024 * 256);
    float* tgt  = alloc(1024 * 256);
    float* nqkv = alloc(1024 * 768);
    float* t1   = alloc(1024 * 256);
    float* t2   = alloc(1024 * 256);
    float* nemb = alloc(1024 * 256);
    float* bnsums = alloc(512);
    float* crT  = alloc(4 * 256);
    float* crO  = alloc(4 * 256);
    float* memb = alloc(1028 * 256);
    float* KV   = alloc(1028 * 512);
    float* etgt = alloc((size_t)LEB * 256);
    float* eqkv = alloc((size_t)LEB * 768);
    float* et1  = alloc((size_t)LEB * 256);
    float* et2  = alloc((size_t)LEB * 256);
    int* grp  = (int*)(wsb + off); off += ((LE * 4 + 255) / 256) * 256;
    int* idxt = (int*)(wsb + off); off += ((LE * 4 + 255) / 256) * 256;

    dim3 blk(16, 16);
    auto gemm = [&](const float* A, const float* W, const float* bi, float* C,
                    int M, int N, int K, int relu) {
        dim3 grid((N + 63) / 64, (M + 63) / 64);
        k_gemm<<<grid, blk, 0, stream>>>(A, W, bi, C, M, N, K, relu);
    };

    k_zero<<<1, 256, 0, stream>>>(out, 1);
    k_zero<<<2, 256, 0, stream>>>(bnsums, 512);
    k_init_tables<<<12, 256, 0, stream>>>(grp, idxt);

    // node input: projection + BN(training stats) + SELU + positional encoding
    gemm(atom_x, Wp, bp, x0, 1024, 256, 54, 0);
    k_bn_part<<<64, 256, 0, stream>>>(x0, bnsums);
    k_bn_selu_pe<<<1024, 256, 0, stream>>>(x0, bnsums, bn_g, bn_b, atom_i, tgt);

    // node decoder: 2 layers
    for (int l = 0; l < 2; l++) {
        gemm(tgt, nd_qkv_w + (size_t)l * 768 * 256, nd_qkv_b + l * 768, nqkv, 1024, 768, 256, 0);
        k_node_attn<<<dim3(256, 8), 128, 0, stream>>>(nqkv, t1);
        gemm(t1, nd_so_w + (size_t)l * 65536, nd_so_b + l * 256, t2, 1024, 256, 256, 0);
        k_add_ln<<<256, 256, 0, stream>>>(tgt, t2, nd_ln_g + (l * 3 + 0) * 256, nd_ln_b + (l * 3 + 0) * 256, tgt, 1024, 0);
        // cross-attn over length-1 memory == broadcast of (z@wv.T+bv)@o_w.T+o_b
        gemm(z,   nd_cqkv_w + (size_t)l * 768 * 256 + 512 * 256, nd_cqkv_b + l * 768 + 512, crT, 4, 256, 256, 0);
        gemm(crT, nd_co_w + (size_t)l * 65536, nd_co_b + l * 256, crO, 4, 256, 256, 0);
        k_add_ln<<<256, 256, 0, stream>>>(tgt, crO, nd_ln_g + (l * 3 + 1) * 256, nd_ln_b + (l * 3 + 1) * 256, tgt, 1024, 1);
        gemm(tgt, nd_ff1_w + (size_t)l * 65536, nd_ff1_b + l * 256, t1, 1024, 256, 256, 1);
        gemm(t1,  nd_ff2_w + (size_t)l * 65536, nd_ff2_b + l * 256, t2, 1024, 256, 256, 0);
        k_add_ln<<<256, 256, 0, stream>>>(tgt, t2, nd_ln_g + (l * 3 + 2) * 256, nd_ln_b + (l * 3 + 2) * 256, tgt, 1024, 0);
    }
    k_add_ln<<<256, 256, 0, stream>>>(tgt, nullptr, nd_fn_g, nd_fn_b, nemb, 1024, 2);

    // node losses (fused 3 heads)
    k_ce_node<<<128, 256, 0, stream>>>(nemb, nc0_w, nc0_b, nc1_w, nc1_b, nc2_w, nc2_b,
                                       atom_y, 1024, 1.f / 1024.f, out);

    // edge path
    k_gather<<<LEB, 256, 0, stream>>>(nemb, idxt, etgt);
    k_build_mem<<<1028, 256, 0, stream>>>(z, nemb, memb);
    gemm(memb, ed_cqkv_w + 256 * 256, ed_cqkv_b + 256, KV, 1028, 512, 256, 0);  // K,V of edge_mem

    gemm(etgt, ed_qkv_w, ed_qkv_b, eqkv, LEB, 768, 256, 0);
    k_edge_self_attn<<<dim3(255, 4), 256, 0, stream>>>(eqkv, et1);
    gemm(et1, ed_so_w, ed_so_b, et2, LEB, 256, 256, 0);
    k_add_ln<<<LEB / 4, 256, 0, stream>>>(etgt, et2, ed_ln_g + 0, ed_ln_b + 0, etgt, LEB, 0);

    gemm(etgt, ed_cqkv_w, ed_cqkv_b, eqkv, LEB, 256, 256, 0);  // q projection (reuse eqkv)
    k_edge_cross_attn<<<dim3(LE, 4), 128, 0, stream>>>(eqkv, KV, grp, et1);
    gemm(et1, ed_co_w, ed_co_b, et2, LEB, 256, 256, 0);
    k_add_ln<<<LEB / 4, 256, 0, stream>>>(etgt, et2, ed_ln_g + 256, ed_ln_b + 256, etgt, LEB, 0);

    gemm(etgt, ed_ff1_w, ed_ff1_b, et1, LEB, 256, 256, 1);
    gemm(et1,  ed_ff2_w, ed_ff2_b, et2, LEB, 256, 256, 0);
    k_add_ln<<<LEB / 4, 256, 0, stream>>>(etgt, et2, ed_ln_g + 512, ed_ln_b + 512, etgt, LEB, 0);
    k_add_ln<<<LEB / 4, 256, 0, stream>>>(etgt, nullptr, ed_fn_g, ed_fn_b, etgt, LEB, 2);

    // edge losses (fused 2 heads)
    k_ce_edge<<<512, 256, 0, stream>>>(etgt, ec0_w, ec0_b, ec1_w, ec1_b,
                                       bond_y, LEB, 1.f / (float)LEB, out);
}

// Round 3
// 703.813 us; speedup vs baseline: 1.8470x; 1.3059x over previous
//
#include <hip/hip_runtime.h>
#include <math.h>

#define SS 256
#define BB 4
#define HH 256
#define LE 2994
#define LEB (LE*BB)
#define SCALE 0.08838834764831845f  // 1/sqrt(128)

typedef __attribute__((ext_vector_type(8))) short bf16x8;
typedef __attribute__((ext_vector_type(4))) float f32x4;

__device__ inline ushort f2b(float f) {   // fp32 -> bf16 RNE
    unsigned u = __float_as_uint(f);
    u += 0x7FFFu + ((u >> 16) & 1u);
    return (ushort)(u >> 16);
}

// ---------------- utility kernels ----------------

__global__ void k_zero(float* p, int n) {
    int i = blockIdx.x * 256 + threadIdx.x;
    if (i < n) p[i] = 0.f;
}

__global__ void k_init_tables(int* __restrict__ grp, int* __restrict__ idxt) {
    int e = blockIdx.x * 256 + threadIdx.x;
    if (e >= LE) return;
    int g, pos;
    if (e < 78) {
        g = (int)((1.0f + sqrtf(8.0f * (float)e + 1.0f)) * 0.5f);
        while (g * (g - 1) / 2 > e) g--;
        while ((g + 1) * g / 2 <= e) g++;
        pos = e - g * (g - 1) / 2;
        idxt[e] = pos;
    } else {
        int r = e - 78;
        g = 13 + r / 12;
        pos = r % 12;
        idxt[e] = g - 12 + pos;
    }
    grp[e] = g;
}

// ---------------- bf16 MFMA GEMM: C[M,N] = A[M,K] @ W[N,K]^T + bias ----------------
// requires N % 128 == 0, K % 32 == 0. 128x128 tile, 4 waves, 4x4 16x16x32 MFMA per wave.

__global__ __launch_bounds__(256) void k_gemm_mfma(
    const float* __restrict__ A, const float* __restrict__ W,
    const float* __restrict__ bias, float* __restrict__ C,
    int M, int N, int K, int relu)
{
    __shared__ ushort As[128 * 32];
    __shared__ ushort Ws[128 * 32];
    int tid = threadIdx.x;
    int wave = tid >> 6, lane = tid & 63;
    int wr = (wave >> 1) * 64, wc = (wave & 1) * 64;
    int m0 = blockIdx.y * 128, n0 = blockIdx.x * 128;
    int q = lane >> 4, p = lane & 15;

    f32x4 acc[4][4];
    #pragma unroll
    for (int i = 0; i < 4; i++)
        #pragma unroll
        for (int j = 0; j < 4; j++) acc[i][j] = (f32x4){0.f, 0.f, 0.f, 0.f};

    int srow = tid >> 1;
    int scol = (tid & 1) << 4;
    const float* Arow = A + (size_t)(m0 + srow) * K + scol;
    const float* Wrow = W + (size_t)(n0 + srow) * K + scol;
    bool aok = (m0 + srow) < M;
    ushort* asd = &As[srow * 32 + scol];
    ushort* wsd = &Ws[srow * 32 + scol];

    for (int k0 = 0; k0 < K; k0 += 32) {
        float av[16], wv[16];
        if (aok) {
            #pragma unroll
            for (int i = 0; i < 4; i++) {
                float4 t4 = *(const float4*)(Arow + k0 + i * 4);
                av[i*4+0] = t4.x; av[i*4+1] = t4.y; av[i*4+2] = t4.z; av[i*4+3] = t4.w;
            }
        } else {
            #pragma unroll
            for (int i = 0; i < 16; i++) av[i] = 0.f;
        }
        #pragma unroll
        for (int i = 0; i < 4; i++) {
            float4 t4 = *(const float4*)(Wrow + k0 + i * 4);
            wv[i*4+0] = t4.x; wv[i*4+1] = t4.y; wv[i*4+2] = t4.z; wv[i*4+3] = t4.w;
        }
        unsigned au[8], wu[8];
        #pragma unroll
        for (int i = 0; i < 8; i++) {
            au[i] = (unsigned)f2b(av[2*i]) | ((unsigned)f2b(av[2*i+1]) << 16);
            wu[i] = (unsigned)f2b(wv[2*i]) | ((unsigned)f2b(wv[2*i+1]) << 16);
        }
        __syncthreads();   // previous tile fully consumed
        ((uint4*)asd)[0] = make_uint4(au[0], au[1], au[2], au[3]);
        ((uint4*)(asd + 8))[0] = make_uint4(au[4], au[5], au[6], au[7]);
        ((uint4*)wsd)[0] = make_uint4(wu[0], wu[1], wu[2], wu[3]);
        ((uint4*)(wsd + 8))[0] = make_uint4(wu[4], wu[5], wu[6], wu[7]);
        __syncthreads();

        bf16x8 afr[4], wfr[4];
        #pragma unroll
        for (int mt = 0; mt < 4; mt++)
            afr[mt] = *(const bf16x8*)&As[(wr + mt * 16 + p) * 32 + q * 8];
        #pragma unroll
        for (int nt = 0; nt < 4; nt++)
            wfr[nt] = *(const bf16x8*)&Ws[(wc + nt * 16 + p) * 32 + q * 8];
        #pragma unroll
        for (int mt = 0; mt < 4; mt++)
            #pragma unroll
            for (int nt = 0; nt < 4; nt++)
                acc[mt][nt] = __builtin_amdgcn_mfma_f32_16x16x32_bf16(afr[mt], wfr[nt], acc[mt][nt], 0, 0, 0);
    }

    #pragma unroll
    for (int mt = 0; mt < 4; mt++) {
        #pragma unroll
        for (int r = 0; r < 4; r++) {
            int grow = m0 + wr + mt * 16 + q * 4 + r;
            if (grow >= M) continue;
            #pragma unroll
            for (int nt = 0; nt < 4; nt++) {
                int gcol = n0 + wc + nt * 16 + p;
                float v = acc[mt][nt][r] + bias[gcol];
                if (relu) v = fmaxf(v, 0.f);
                C[(size_t)grow * N + gcol] = v;
            }
        }
    }
}

// ---------------- generic fp32 GEMM (small/odd shapes only) ----------------

__global__ __launch_bounds__(256) void k_gemm(
    const float* __restrict__ A, const float* __restrict__ W,
    const float* __restrict__ bias, float* __restrict__ C,
    int M, int N, int K, int relu)
{
    __shared__ __align__(16) float As[16][68];
    __shared__ __align__(16) float Ws[16][68];
    int tx = threadIdx.x, ty = threadIdx.y;
    int tid = ty * 16 + tx;
    int m0 = blockIdx.y * 64, n0 = blockIdx.x * 64;
    float acc[4][4] = {{0.f}};
    int r  = tid >> 2;
    int kk = (tid & 3) << 2;
    bool k4 = ((K & 3) == 0);
    for (int k0 = 0; k0 < K; k0 += 16) {
        float4 av = make_float4(0.f, 0.f, 0.f, 0.f);
        float4 wv = make_float4(0.f, 0.f, 0.f, 0.f);
        int gm = m0 + r, gk = k0 + kk;
        if (gm < M) {
            if (k4 && gk + 4 <= K) av = *(const float4*)(A + (size_t)gm * K + gk);
            else {
                float tv[4];
                for (int i = 0; i < 4; i++) tv[i] = (gk + i < K) ? A[(size_t)gm * K + gk + i] : 0.f;
                av = make_float4(tv[0], tv[1], tv[2], tv[3]);
            }
        }
        int gn = n0 + r;
        if (gn < N) {
            if (k4 && gk + 4 <= K) wv = *(const float4*)(W + (size_t)gn * K + gk);
            else {
                float tv[4];
                for (int i = 0; i < 4; i++) tv[i] = (gk + i < K) ? W[(size_t)gn * K + gk + i] : 0.f;
                wv = make_float4(tv[0], tv[1], tv[2], tv[3]);
            }
        }
        As[kk + 0][r] = av.x; As[kk + 1][r] = av.y; As[kk + 2][r] = av.z; As[kk + 3][r] = av.w;
        Ws[kk + 0][r] = wv.x; Ws[kk + 1][r] = wv.y; Ws[kk + 2][r] = wv.z; Ws[kk + 3][r] = wv.w;
        __syncthreads();
        #pragma unroll
        for (int k = 0; k < 16; k++) {
            float4 a4 = *(const float4*)&As[k][ty << 2];
            float4 b4 = *(const float4*)&Ws[k][tx << 2];
            float a[4] = {a4.x, a4.y, a4.z, a4.w};
            float b[4] = {b4.x, b4.y, b4.z, b4.w};
            #pragma unroll
            for (int i = 0; i < 4; i++)
                #pragma unroll
                for (int j = 0; j < 4; j++)
                    acc[i][j] = fmaf(a[i], b[j], acc[i][j]);
        }
        __syncthreads();
    }
    #pragma unroll
    for (int i = 0; i < 4; i++) {
        int gm = m0 + (ty << 2) + i;
        if (gm >= M) continue;
        #pragma unroll
        for (int j = 0; j < 4; j++) {
            int gn = n0 + (tx << 2) + j;
            if (gn >= N) continue;
            float v = acc[i][j] + bias[gn];
            if (relu) v = fmaxf(v, 0.f);
            C[(size_t)gm * N + gn] = v;
        }
    }
}

// ---------------- residual + LayerNorm (wave per row, 4 rows/block) ----------------

__global__ __launch_bounds__(256) void k_add_ln(
    const float* __restrict__ x, const float* __restrict__ delta,
    const float* __restrict__ g, const float* __restrict__ bta,
    float* __restrict__ out, int M, int mode)
{
    int row = blockIdx.x * 4 + (threadIdx.x >> 6);
    int t = threadIdx.x & 63;
    if (row >= M) return;
    float4 v = ((const float4*)(x + (size_t)row * HH))[t];
    if (mode == 0) {
        float4 d = ((const float4*)(delta + (size_t)row * HH))[t];
        v.x += d.x; v.y += d.y; v.z += d.z; v.w += d.w;
    } else if (mode == 1) {
        float4 d = ((const float4*)(delta + (size_t)(row & 3) * HH))[t];
        v.x += d.x; v.y += d.y; v.z += d.z; v.w += d.w;
    }
    float s = v.x + v.y + v.z + v.w;
    for (int o = 32; o; o >>= 1) s += __shfl_down(s, o);
    float mean = __shfl(s, 0) * (1.f / 256.f);
    float cx = v.x - mean, cy = v.y - mean, cz = v.z - mean, cw = v.w - mean;
    float q = cx * cx + cy * cy + cz * cz + cw * cw;
    for (int o = 32; o; o >>= 1) q += __shfl_down(q, o);
    float rstd = rsqrtf(__shfl(q, 0) * (1.f / 256.f) + 1e-5f);
    float4 gg = ((const float4*)g)[t];
    float4 bb = ((const float4*)bta)[t];
    float4 o4;
    o4.x = cx * rstd * gg.x + bb.x;
    o4.y = cy * rstd * gg.y + bb.y;
    o4.z = cz * rstd * gg.z + bb.z;
    o4.w = cw * rstd * gg.w + bb.w;
    ((float4*)(out + (size_t)row * HH))[t] = o4;
}

// ---------------- BatchNorm partial sums ----------------

__global__ __launch_bounds__(256) void k_bn_part(const float* __restrict__ x, float* __restrict__ sums) {
    int t = threadIdx.x;
    int r0 = blockIdx.x * 16;
    float s = 0.f, s2 = 0.f;
    for (int r = r0; r < r0 + 16; r++) {
        float v = x[(size_t)r * 256 + t];
        s += v; s2 += v * v;
    }
    atomicAdd(&sums[t], s);
    atomicAdd(&sums[256 + t], s2);
}

// ---------------- BN-finalize + SELU + positional encoding ----------------

__global__ __launch_bounds__(256) void k_bn_selu_pe(
    const float* __restrict__ x0, const float* __restrict__ sums,
    const float* __restrict__ g, const float* __restrict__ b,
    const int* __restrict__ atom_i, float* __restrict__ out)
{
    int row = blockIdx.x, t = threadIdx.x;
    float m = sums[t] * (1.f / 1024.f);
    float var = sums[256 + t] * (1.f / 1024.f) - m * m;
    float rstd = rsqrtf(var + 1e-5f);
    float v = x0[(size_t)row * 256 + t];
    v = (v - m) * rstd * g[t] + b[t];
    const float SC = 1.0507009873554805f, AL = 1.6732632423543772f;
    v = SC * (v > 0.f ? v : AL * expm1f(v));
    float pos = (float)atom_i[row];
    float freq = expf(-(float)t * (9.210340371976184f / 256.f));
    float ang = pos * freq;
    float pe = (t & 1) ? cosf(ang) : sinf(ang);
    out[(size_t)row * 256 + t] = v + pe;
}

// ---------------- node causal self-attention ----------------

__global__ __launch_bounds__(128) void k_node_attn(
    const float* __restrict__ qkv, float* __restrict__ out)
{
    int q = blockIdx.x;
    int b = blockIdx.y >> 1, h = blockIdx.y & 1;
    int t = threadIdx.x;
    __shared__ float qv[128];
    __shared__ float sc[256];
    __shared__ float red[128];
    size_t rq = ((size_t)q * BB + b) * 768 + h * 128;
    qv[t] = qkv[rq + t];
    __syncthreads();
    for (int k = t; k < 256; k += 128) {
        float sv = -1e30f;
        if (k <= q) {
            const float* kp = qkv + ((size_t)k * BB + b) * 768 + 256 + h * 128;
            float acc = 0.f;
            for (int d = 0; d < 128; d++) acc = fmaf(qv[d], kp[d], acc);
            sv = acc * SCALE;
        }
        sc[k] = sv;
    }
    __syncthreads();
    red[t] = fmaxf(sc[t], sc[t + 128]);
    __syncthreads();
    for (int o = 64; o; o >>= 1) { if (t < o) red[t] = fmaxf(red[t], red[t + o]); __syncthreads(); }
    float m = red[0];
    __syncthreads();
    float e0 = expf(sc[t] - m), e1 = expf(sc[t + 128] - m);
    sc[t] = e0; sc[t + 128] = e1;
    red[t] = e0 + e1;
    __syncthreads();
    for (int o = 64; o; o >>= 1) { if (t < o) red[t] += red[t + o]; __syncthreads(); }
    float inv = 1.f / red[0];
    float acc = 0.f;
    const float* vp = qkv + (size_t)b * 768 + 512 + h * 128 + t;
    for (int k = 0; k <= q; k++) acc = fmaf(sc[k], vp[(size_t)k * BB * 768], acc);
    out[((size_t)q * BB + b) * 256 + h * 128 + t] = acc * inv;
}

// ---------------- edge group self-attention ----------------

__global__ __launch_bounds__(256) void k_edge_self_attn(
    const float* __restrict__ qkv, float* __restrict__ out)
{
    int g = blockIdx.x + 1;
    int b = blockIdx.y;
    int gs = min(g, 12);
    int base = (g <= 13) ? g * (g - 1) / 2 : 78 + (g - 13) * 12;
    int h = threadIdx.x >> 7;
    int t = threadIdx.x & 127;
    __shared__ float qs[2][12][128], ks[2][12][128], vs[2][12][128];
    __shared__ float ps[2][12][12];
    for (int i = 0; i < gs; i++) {
        size_t row = ((size_t)(base + i) * BB + b) * 768 + h * 128 + t;
        qs[h][i][t] = qkv[row];
        ks[h][i][t] = qkv[row + 256];
        vs[h][i][t] = qkv[row + 512];
    }
    __syncthreads();
    for (int p = t; p < gs * gs; p += 128) {
        int i = p / gs, j = p - i * gs;
        float acc = 0.f;
        for (int d = 0; d < 128; d++) acc = fmaf(qs[h][i][d], ks[h][j][d], acc);
        ps[h][i][j] = acc * SCALE;
    }
    __syncthreads();
    if (t < gs) {
        float m = -1e30f;
        for (int j = 0; j < gs; j++) m = fmaxf(m, ps[h][t][j]);
        float e[12]; float s = 0.f;
        for (int j = 0; j < gs; j++) { e[j] = expf(ps[h][t][j] - m); s += e[j]; }
        float inv = 1.f / s;
        for (int j = 0; j < gs; j++) ps[h][t][j] = e[j] * inv;
    }
    __syncthreads();
    for (int i = 0; i < gs; i++) {
        float acc = 0.f;
        for (int j = 0; j < gs; j++) acc = fmaf(ps[h][i][j], vs[h][j][t], acc);
        out[((size_t)(base + i) * BB + b) * 256 + h * 128 + t] = acc;
    }
}

// ---------------- edge 2-key cross-attention ----------------

__global__ __launch_bounds__(128) void k_edge_cross_attn(
    const float* __restrict__ Q, const float* __restrict__ KV,
    const int* __restrict__ grp, float* __restrict__ out)
{
    int e = blockIdx.x, b = blockIdx.y;
    int h = threadIdx.x >> 6, l = threadIdx.x & 63;
    int g = grp[e];
    size_t qrow = ((size_t)e * BB + b) * 256 + h * 128;
    float qa = Q[qrow + l], qb = Q[qrow + 64 + l];
    size_t k0r = (size_t)b * 512 + h * 128;
    size_t k1r = ((size_t)(g + 1) * BB + b) * 512 + h * 128;
    float p0 = qa * KV[k0r + l] + qb * KV[k0r + 64 + l];
    float p1 = qa * KV[k1r + l] + qb * KV[k1r + 64 + l];
    for (int o = 32; o; o >>= 1) { p0 += __shfl_down(p0, o); p1 += __shfl_down(p1, o); }
    p0 = __shfl(p0, 0) * SCALE;
    p1 = __shfl(p1, 0) * SCALE;
    float m = fmaxf(p0, p1);
    float e0 = expf(p0 - m), e1 = expf(p1 - m);
    float inv = 1.f / (e0 + e1);
    e0 *= inv; e1 *= inv;
    out[qrow + l]      = e0 * KV[k0r + 256 + l]      + e1 * KV[k1r + 256 + l];
    out[qrow + 64 + l] = e0 * KV[k0r + 256 + 64 + l] + e1 * KV[k1r + 256 + 64 + l];
}

// ---------------- gathers ----------------

__global__ __launch_bounds__(256) void k_gather(
    const float* __restrict__ src, const int* __restrict__ idxt, float* __restrict__ dst)
{
    int r = blockIdx.x, t = threadIdx.x;
    int e = r >> 2, b = r & 3;
    dst[(size_t)r * 256 + t] = src[((size_t)idxt[e] * 4 + b) * 256 + t];
}

__global__ __launch_bounds__(256) void k_build_mem(
    const float* __restrict__ z, const float* __restrict__ nemb, float* __restrict__ mem)
{
    int r = blockIdx.x, t = threadIdx.x;
    int m = r >> 2, b = r & 3;
    mem[(size_t)r * 256 + t] = (m == 0) ? z[(size_t)b * 256 + t]
                                        : nemb[((size_t)(m - 1) * 4 + b) * 256 + t];
}

// ---------------- fused cross-entropy ----------------

__global__ __launch_bounds__(256) void k_ce_node(
    const float* __restrict__ emb,
    const float* __restrict__ w0, const float* __restrict__ b0,
    const float* __restrict__ w1, const float* __restrict__ b1,
    const float* __restrict__ w2, const float* __restrict__ b2,
    const int* __restrict__ y, int M, float invM, float* __restrict__ lossOut)
{
    int wave = threadIdx.x >> 6, lane = threadIdx.x & 63;
    int wid = blockIdx.x * 4 + wave;
    float local = 0.f;
    for (int r = wid; r < M; r += gridDim.x * 4) {
        float4 x = ((const float4*)(emb + (size_t)r * 256))[lane];
        float acc[54];
        #pragma unroll
        for (int c = 0; c < 40; c++) {
            float4 wv = ((const float4*)(w0 + (size_t)c * 256))[lane];
            acc[c] = x.x * wv.x + x.y * wv.y + x.z * wv.z + x.w * wv.w;
        }
        #pragma unroll
        for (int c = 0; c < 8; c++) {
            float4 wv = ((const float4*)(w1 + (size_t)c * 256))[lane];
            acc[40 + c] = x.x * wv.x + x.y * wv.y + x.z * wv.z + x.w * wv.w;
        }
        #pragma unroll
        for (int c = 0; c < 6; c++) {
            float4 wv = ((const float4*)(w2 + (size_t)c * 256))[lane];
            acc[48 + c] = x.x * wv.x + x.y * wv.y + x.z * wv.z + x.w * wv.w;
        }
        #pragma unroll
        for (int c = 0; c < 54; c++)
            for (int o = 32; o; o >>= 1) acc[c] += __shfl_down(acc[c], o);
        if (lane == 0) {
            int y0 = y[(size_t)r * 3 + 0], y1 = y[(size_t)r * 3 + 1], y2 = y[(size_t)r * 3 + 2];
            float m0 = -1e30f, m1 = -1e30f, m2 = -1e30f;
            float lg[54];
            for (int c = 0; c < 40; c++) { lg[c] = acc[c] + b0[c]; m0 = fmaxf(m0, lg[c]); }
            for (int c = 0; c < 8; c++)  { lg[40 + c] = acc[40 + c] + b1[c]; m1 = fmaxf(m1, lg[40 + c]); }
            for (int c = 0; c < 6; c++)  { lg[48 + c] = acc[48 + c] + b2[c]; m2 = fmaxf(m2, lg[48 + c]); }
            float s0 = 0.f, s1 = 0.f, s2 = 0.f;
            for (int c = 0; c < 40; c++) s0 += expf(lg[c] - m0);
            for (int c = 0; c < 8; c++)  s1 += expf(lg[40 + c] - m1);
            for (int c = 0; c < 6; c++)  s2 += expf(lg[48 + c] - m2);
            local += (m0 + logf(s0) - lg[y0]) + (m1 + logf(s1) - lg[40 + y1]) + (m2 + logf(s2) - lg[48 + y2]);
        }
    }
    __shared__ float ls[4];
    if (lane == 0) ls[wave] = local;
    __syncthreads();
    if (threadIdx.x == 0)
        atomicAdd(lossOut, (ls[0] + ls[1] + ls[2] + ls[3]) * invM);
}

__global__ __launch_bounds__(256) void k_ce_edge(
    const float* __restrict__ emb,
    const float* __restrict__ w0, const float* __restrict__ b0,
    const float* __restrict__ w1, const float* __restrict__ b1,
    const int* __restrict__ y, int M, float invM, float* __restrict__ lossOut)
{
    int wave = threadIdx.x >> 6, lane = threadIdx.x & 63;
    int wid = blockIdx.x * 4 + wave;
    float local = 0.f;
    for (int r = wid; r < M; r += gridDim.x * 4) {
        float4 x = ((const float4*)(emb + (size_t)r * 256))[lane];
        float acc[9];
        #pragma unroll
        for (int c = 0; c < 5; c++) {
            float4 wv = ((const float4*)(w0 + (size_t)c * 256))[lane];
            acc[c] = x.x * wv.x + x.y * wv.y + x.z * wv.z + x.w * wv.w;
        }
        #pragma unroll
        for (int c = 0; c < 4; c++) {
            float4 wv = ((const float4*)(w1 + (size_t)c * 256))[lane];
            acc[5 + c] = x.x * wv.x + x.y * wv.y + x.z * wv.z + x.w * wv.w;
        }
        #pragma unroll
        for (int c = 0; c < 9; c++)
            for (int o = 32; o; o >>= 1) acc[c] += __shfl_down(acc[c], o);
        if (lane == 0) {
            int y0 = y[(size_t)r * 2 + 0], y1 = y[(size_t)r * 2 + 1];
            float lg[9];
            float m0 = -1e30f, m1 = -1e30f;
            for (int c = 0; c < 5; c++) { lg[c] = acc[c] + b0[c]; m0 = fmaxf(m0, lg[c]); }
            for (int c = 0; c < 4; c++) { lg[5 + c] = acc[5 + c] + b1[c]; m1 = fmaxf(m1, lg[5 + c]); }
            float s0 = 0.f, s1 = 0.f;
            for (int c = 0; c < 5; c++) s0 += expf(lg[c] - m0);
            for (int c = 0; c < 4; c++) s1 += expf(lg[5 + c] - m1);
            local += (m0 + logf(s0) - lg[y0]) + (m1 + logf(s1) - lg[5 + y1]);
        }
    }
    __shared__ float ls[4];
    if (lane == 0) ls[wave] = local;
    __syncthreads();
    if (threadIdx.x == 0)
        atomicAdd(lossOut, (ls[0] + ls[1] + ls[2] + ls[3]) * invM);
}

// ---------------- host ----------------

extern "C" void kernel_launch(void* const* d_in, const int* in_sizes, int n_in,
                              void* d_out, int out_size, void* d_ws, size_t ws_size,
                              hipStream_t stream)
{
    (void)in_sizes; (void)n_in; (void)out_size; (void)ws_size;
    const float* z        = (const float*)d_in[0];
    const int*   atom_i   = (const int*)d_in[1];
    const float* atom_x   = (const float*)d_in[2];
    const int*   atom_y   = (const int*)d_in[3];
    const int*   bond_y   = (const int*)d_in[4];
    const float* Wp       = (const float*)d_in[5];
    const float* bp       = (const float*)d_in[6];
    const float* bn_g     = (const float*)d_in[7];
    const float* bn_b     = (const float*)d_in[8];
    const float* nd_qkv_w = (const float*)d_in[9];
    const float* nd_qkv_b = (const float*)d_in[10];
    const float* nd_so_w  = (const float*)d_in[11];
    const float* nd_so_b  = (const float*)d_in[12];
    const float* nd_cqkv_w= (const float*)d_in[13];
    const float* nd_cqkv_b= (const float*)d_in[14];
    const float* nd_co_w  = (const float*)d_in[15];
    const float* nd_co_b  = (const float*)d_in[16];
    const float* nd_ff1_w = (const float*)d_in[17];
    const float* nd_ff1_b = (const float*)d_in[18];
    const float* nd_ff2_w = (const float*)d_in[19];
    const float* nd_ff2_b = (const float*)d_in[20];
    const float* nd_ln_g  = (const float*)d_in[21];
    const float* nd_ln_b  = (const float*)d_in[22];
    const float* nd_fn_g  = (const float*)d_in[23];
    const float* nd_fn_b  = (const float*)d_in[24];
    const float* ed_qkv_w = (const float*)d_in[25];
    const float* ed_qkv_b = (const float*)d_in[26];
    const float* ed_so_w  = (const float*)d_in[27];
    const float* ed_so_b  = (const float*)d_in[28];
    const float* ed_cqkv_w= (const float*)d_in[29];
    const float* ed_cqkv_b= (const float*)d_in[30];
    const float* ed_co_w  = (const float*)d_in[31];
    const float* ed_co_b  = (const float*)d_in[32];
    const float* ed_ff1_w = (const float*)d_in[33];
    const float* ed_ff1_b = (const float*)d_in[34];
    const float* ed_ff2_w = (const float*)d_in[35];
    const float* ed_ff2_b = (const float*)d_in[36];
    const float* ed_ln_g  = (const float*)d_in[37];
    const float* ed_ln_b  = (const float*)d_in[38];
    const float* ed_fn_g  = (const float*)d_in[39];
    const float* ed_fn_b  = (const float*)d_in[40];
    const float* nc0_w = (const float*)d_in[41]; const float* nc0_b = (const float*)d_in[42];
    const float* nc1_w = (const float*)d_in[43]; const float* nc1_b = (const float*)d_in[44];
    const float* nc2_w = (const float*)d_in[45]; const float* nc2_b = (const float*)d_in[46];
    const float* ec0_w = (const float*)d_in[47]; const float* ec0_b = (const float*)d_in[48];
    const float* ec1_w = (const float*)d_in[49]; const float* ec1_b = (const float*)d_in[50];

    float* out = (float*)d_out;

    char* wsb = (char*)d_ws;
    size_t off = 0;
    auto alloc = [&](size_t nfloats) -> float* {
        float* p = (float*)(wsb + off);
        off += ((nfloats * 4 + 255) / 256) * 256;
        return p;
    };
    float* x0   = alloc(1024 * 256);
    float* tgt  = alloc(1024 * 256);
    float* nqkv = alloc(1024 * 768);
    float* t1   = alloc(1024 * 256);
    float* t2   = alloc(1024 * 256);
    float* nemb = alloc(1024 * 256);
    float* bnsums = alloc(512);
    float* crT  = alloc(4 * 256);
    float* crO  = alloc(4 * 256);
    float* memb = alloc(1028 * 256);
    float* KV   = alloc(1028 * 512);
    float* etgt = alloc((size_t)LEB * 256);
    float* eqkv = alloc((size_t)LEB * 768);
    float* et1  = alloc((size_t)LEB * 256);
    float* et2  = alloc((size_t)LEB * 256);
    int* grp  = (int*)(wsb + off); off += ((LE * 4 + 255) / 256) * 256;
    int* idxt = (int*)(wsb + off); off += ((LE * 4 + 255) / 256) * 256;

    dim3 blk(16, 16);
    auto gemm = [&](const float* A, const float* W, const float* bi, float* C,
                    int M, int N, int K, int relu) {
        dim3 grid((N + 63) / 64, (M + 63) / 64);
        k_gemm<<<grid, blk, 0, stream>>>(A, W, bi, C, M, N, K, relu);
    };
    auto gemm_bf = [&](const float* A, const float* W, const float* bi, float* C,
                       int M, int N, int K, int relu) {
        dim3 grid(N / 128, (M + 127) / 128);
        k_gemm_mfma<<<grid, 256, 0, stream>>>(A, W, bi, C, M, N, K, relu);
    };

    k_zero<<<1, 256, 0, stream>>>(out, 1);
    k_zero<<<2, 256, 0, stream>>>(bnsums, 512);
    k_init_tables<<<12, 256, 0, stream>>>(grp, idxt);

    // node input: projection + BN(training stats) + SELU + positional encoding
    gemm(atom_x, Wp, bp, x0, 1024, 256, 54, 0);
    k_bn_part<<<64, 256, 0, stream>>>(x0, bnsums);
    k_bn_selu_pe<<<1024, 256, 0, stream>>>(x0, bnsums, bn_g, bn_b, atom_i, tgt);

    // node decoder: 2 layers
    for (int l = 0; l < 2; l++) {
        gemm_bf(tgt, nd_qkv_w + (size_t)l * 768 * 256, nd_qkv_b + l * 768, nqkv, 1024, 768, 256, 0);
        k_node_attn<<<dim3(256, 8), 128, 0, stream>>>(nqkv, t1);
        gemm_bf(t1, nd_so_w + (size_t)l * 65536, nd_so_b + l * 256, t2, 1024, 256, 256, 0);
        k_add_ln<<<256, 256, 0, stream>>>(tgt, t2, nd_ln_g + (l * 3 + 0) * 256, nd_ln_b + (l * 3 + 0) * 256, tgt, 1024, 0);
        gemm(z,   nd_cqkv_w + (size_t)l * 768 * 256 + 512 * 256, nd_cqkv_b + l * 768 + 512, crT, 4, 256, 256, 0);
        gemm(crT, nd_co_w + (size_t)l * 65536, nd_co_b + l * 256, crO, 4, 256, 256, 0);
        k_add_ln<<<256, 256, 0, stream>>>(tgt, crO, nd_ln_g + (l * 3 + 1) * 256, nd_ln_b + (l * 3 + 1) * 256, tgt, 1024, 1);
        gemm_bf(tgt, nd_ff1_w + (size_t)l * 65536, nd_ff1_b + l * 256, t1, 1024, 256, 256, 1);
        gemm_bf(t1,  nd_ff2_w + (size_t)l * 65536, nd_ff2_b + l * 256, t2, 1024, 256, 256, 0);
        k_add_ln<<<256, 256, 0, stream>>>(tgt, t2, nd_ln_g + (l * 3 + 2) * 256, nd_ln_b + (l * 3 + 2) * 256, tgt, 1024, 0);
    }
    k_add_ln<<<256, 256, 0, stream>>>(tgt, nullptr, nd_fn_g, nd_fn_b, nemb, 1024, 2);

    // node losses
    k_ce_node<<<128, 256, 0, stream>>>(nemb, nc0_w, nc0_b, nc1_w, nc1_b, nc2_w, nc2_b,
                                       atom_y, 1024, 1.f / 1024.f, out);

    // edge path
    k_gather<<<LEB, 256, 0, stream>>>(nemb, idxt, etgt);
    k_build_mem<<<1028, 256, 0, stream>>>(z, nemb, memb);
    gemm_bf(memb, ed_cqkv_w + 256 * 256, ed_cqkv_b + 256, KV, 1028, 512, 256, 0);

    gemm_bf(etgt, ed_qkv_w, ed_qkv_b, eqkv, LEB, 768, 256, 0);
    k_edge_self_attn<<<dim3(255, 4), 256, 0, stream>>>(eqkv, et1);
    gemm_bf(et1, ed_so_w, ed_so_b, et2, LEB, 256, 256, 0);
    k_add_ln<<<LEB / 4, 256, 0, stream>>>(etgt, et2, ed_ln_g + 0, ed_ln_b + 0, etgt, LEB, 0);

    gemm_bf(etgt, ed_cqkv_w, ed_cqkv_b, eqkv, LEB, 256, 256, 0);
    k_edge_cross_attn<<<dim3(LE, 4), 128, 0, stream>>>(eqkv, KV, grp, et1);
    gemm_bf(et1, ed_co_w, ed_co_b, et2, LEB, 256, 256, 0);
    k_add_ln<<<LEB / 4, 256, 0, stream>>>(etgt, et2, ed_ln_g + 256, ed_ln_b + 256, etgt, LEB, 0);

    gemm_bf(etgt, ed_ff1_w, ed_ff1_b, et1, LEB, 256, 256, 1);
    gemm_bf(et1,  ed_ff2_w, ed_ff2_b, et2, LEB, 256, 256, 0);
    k_add_ln<<<LEB / 4, 256, 0, stream>>>(etgt, et2, ed_ln_g + 512, ed_ln_b + 512, etgt, LEB, 0);
    k_add_ln<<<LEB / 4, 256, 0, stream>>>(etgt, nullptr, ed_fn_g, ed_fn_b, etgt, LEB, 2);

    // edge losses
    k_ce_edge<<<512, 256, 0, stream>>>(etgt, ec0_w, ec0_b, ec1_w, ec1_b,
                                       bond_y, LEB, 1.f / (float)LEB, out);
}

// Round 4
// 671.727 us; speedup vs baseline: 1.9352x; 1.0478x over previous
//
#include <hip/hip_runtime.h>
#include <math.h>

#define SS 256
#define BB 4
#define HH 256
#define LE 2994
#define LEB (LE*BB)
#define SCALE 0.08838834764831845f  // 1/sqrt(128)

typedef __attribute__((ext_vector_type(8))) short bf16x8;
typedef __attribute__((ext_vector_type(4))) float f32x4;

__device__ inline ushort f2b(float f) {   // fp32 -> bf16 RNE
    unsigned u = __float_as_uint(f);
    u += 0x7FFFu + ((u >> 16) & 1u);
    return (ushort)(u >> 16);
}

// ---------------- utility kernels ----------------

__global__ void k_zero(float* p, int n) {
    int i = blockIdx.x * 256 + threadIdx.x;
    if (i < n) p[i] = 0.f;
}

__global__ void k_init_tables(int* __restrict__ grp, int* __restrict__ idxt) {
    int e = blockIdx.x * 256 + threadIdx.x;
    if (e >= LE) return;
    int g, pos;
    if (e < 78) {
        g = (int)((1.0f + sqrtf(8.0f * (float)e + 1.0f)) * 0.5f);
        while (g * (g - 1) / 2 > e) g--;
        while ((g + 1) * g / 2 <= e) g++;
        pos = e - g * (g - 1) / 2;
        idxt[e] = pos;
    } else {
        int r = e - 78;
        g = 13 + r / 12;
        pos = r % 12;
        idxt[e] = g - 12 + pos;
    }
    grp[e] = g;
}

// ---------------- bf16 MFMA GEMM: C[M,N] = A[M,K] @ W[N,K]^T + bias ----------------

__global__ __launch_bounds__(256) void k_gemm_mfma(
    const float* __restrict__ A, const float* __restrict__ W,
    const float* __restrict__ bias, float* __restrict__ C,
    int M, int N, int K, int relu)
{
    __shared__ ushort As[128 * 32];
    __shared__ ushort Ws[128 * 32];
    int tid = threadIdx.x;
    int wave = tid >> 6, lane = tid & 63;
    int wr = (wave >> 1) * 64, wc = (wave & 1) * 64;
    int m0 = blockIdx.y * 128, n0 = blockIdx.x * 128;
    int q = lane >> 4, p = lane & 15;

    f32x4 acc[4][4];
    #pragma unroll
    for (int i = 0; i < 4; i++)
        #pragma unroll
        for (int j = 0; j < 4; j++) acc[i][j] = (f32x4){0.f, 0.f, 0.f, 0.f};

    int srow = tid >> 1;
    int scol = (tid & 1) << 4;
    const float* Arow = A + (size_t)(m0 + srow) * K + scol;
    const float* Wrow = W + (size_t)(n0 + srow) * K + scol;
    bool aok = (m0 + srow) < M;
    ushort* asd = &As[srow * 32 + scol];
    ushort* wsd = &Ws[srow * 32 + scol];

    for (int k0 = 0; k0 < K; k0 += 32) {
        float av[16], wv[16];
        if (aok) {
            #pragma unroll
            for (int i = 0; i < 4; i++) {
                float4 t4 = *(const float4*)(Arow + k0 + i * 4);
                av[i*4+0] = t4.x; av[i*4+1] = t4.y; av[i*4+2] = t4.z; av[i*4+3] = t4.w;
            }
        } else {
            #pragma unroll
            for (int i = 0; i < 16; i++) av[i] = 0.f;
        }
        #pragma unroll
        for (int i = 0; i < 4; i++) {
            float4 t4 = *(const float4*)(Wrow + k0 + i * 4);
            wv[i*4+0] = t4.x; wv[i*4+1] = t4.y; wv[i*4+2] = t4.z; wv[i*4+3] = t4.w;
        }
        unsigned au[8], wu[8];
        #pragma unroll
        for (int i = 0; i < 8; i++) {
            au[i] = (unsigned)f2b(av[2*i]) | ((unsigned)f2b(av[2*i+1]) << 16);
            wu[i] = (unsigned)f2b(wv[2*i]) | ((unsigned)f2b(wv[2*i+1]) << 16);
        }
        __syncthreads();
        ((uint4*)asd)[0] = make_uint4(au[0], au[1], au[2], au[3]);
        ((uint4*)(asd + 8))[0] = make_uint4(au[4], au[5], au[6], au[7]);
        ((uint4*)wsd)[0] = make_uint4(wu[0], wu[1], wu[2], wu[3]);
        ((uint4*)(wsd + 8))[0] = make_uint4(wu[4], wu[5], wu[6], wu[7]);
        __syncthreads();

        bf16x8 afr[4], wfr[4];
        #pragma unroll
        for (int mt = 0; mt < 4; mt++)
            afr[mt] = *(const bf16x8*)&As[(wr + mt * 16 + p) * 32 + q * 8];
        #pragma unroll
        for (int nt = 0; nt < 4; nt++)
            wfr[nt] = *(const bf16x8*)&Ws[(wc + nt * 16 + p) * 32 + q * 8];
        #pragma unroll
        for (int mt = 0; mt < 4; mt++)
            #pragma unroll
            for (int nt = 0; nt < 4; nt++)
                acc[mt][nt] = __builtin_amdgcn_mfma_f32_16x16x32_bf16(afr[mt], wfr[nt], acc[mt][nt], 0, 0, 0);
    }

    #pragma unroll
    for (int mt = 0; mt < 4; mt++) {
        #pragma unroll
        for (int r = 0; r < 4; r++) {
            int grow = m0 + wr + mt * 16 + q * 4 + r;
            if (grow >= M) continue;
            #pragma unroll
            for (int nt = 0; nt < 4; nt++) {
                int gcol = n0 + wc + nt * 16 + p;
                float v = acc[mt][nt][r] + bias[gcol];
                if (relu) v = fmaxf(v, 0.f);
                C[(size_t)grow * N + gcol] = v;
            }
        }
    }
}

// ---------------- node attention, MFMA path ----------------
// qkv layout: row (s*4+b) of 768 floats = [q|k|v], head h at offset h*128.
// batch z = b*2 + h.

// S[z][q][k] = sum_d Q * K  (raw dot; scale+mask in softmax)
__global__ __launch_bounds__(256) void k_attn_qk(
    const float* __restrict__ qkv, float* __restrict__ S)
{
    __shared__ ushort As[128 * 32];
    __shared__ ushort Ws[128 * 32];
    int tid = threadIdx.x;
    int wave = tid >> 6, lane = tid & 63;
    int wr = (wave >> 1) * 64, wc = (wave & 1) * 64;
    int m0 = blockIdx.y * 128, n0 = blockIdx.x * 128;
    int z = blockIdx.z, b = z >> 1, h = z & 1;
    int q = lane >> 4, p = lane & 15;
    size_t boff = (size_t)b * 768 + h * 128;

    f32x4 acc[4][4];
    #pragma unroll
    for (int i = 0; i < 4; i++)
        #pragma unroll
        for (int j = 0; j < 4; j++) acc[i][j] = (f32x4){0.f, 0.f, 0.f, 0.f};

    int srow = tid >> 1;
    int scol = (tid & 1) << 4;
    const float* Arow = qkv + (size_t)(m0 + srow) * 3072 + boff + scol;         // Q
    const float* Wrow = qkv + (size_t)(n0 + srow) * 3072 + boff + 256 + scol;   // K
    ushort* asd = &As[srow * 32 + scol];
    ushort* wsd = &Ws[srow * 32 + scol];

    for (int k0 = 0; k0 < 128; k0 += 32) {
        float av[16], wv[16];
        #pragma unroll
        for (int i = 0; i < 4; i++) {
            float4 a4 = *(const float4*)(Arow + k0 + i * 4);
            float4 w4 = *(const float4*)(Wrow + k0 + i * 4);
            av[i*4+0] = a4.x; av[i*4+1] = a4.y; av[i*4+2] = a4.z; av[i*4+3] = a4.w;
            wv[i*4+0] = w4.x; wv[i*4+1] = w4.y; wv[i*4+2] = w4.z; wv[i*4+3] = w4.w;
        }
        unsigned au[8], wu[8];
        #pragma unroll
        for (int i = 0; i < 8; i++) {
            au[i] = (unsigned)f2b(av[2*i]) | ((unsigned)f2b(av[2*i+1]) << 16);
            wu[i] = (unsigned)f2b(wv[2*i]) | ((unsigned)f2b(wv[2*i+1]) << 16);
        }
        __syncthreads();
        ((uint4*)asd)[0] = make_uint4(au[0], au[1], au[2], au[3]);
        ((uint4*)(asd + 8))[0] = make_uint4(au[4], au[5], au[6], au[7]);
        ((uint4*)wsd)[0] = make_uint4(wu[0], wu[1], wu[2], wu[3]);
        ((uint4*)(wsd + 8))[0] = make_uint4(wu[4], wu[5], wu[6], wu[7]);
        __syncthreads();

        bf16x8 afr[4], wfr[4];
        #pragma unroll
        for (int mt = 0; mt < 4; mt++)
            afr[mt] = *(const bf16x8*)&As[(wr + mt * 16 + p) * 32 + q * 8];
        #pragma unroll
        for (int nt = 0; nt < 4; nt++)
            wfr[nt] = *(const bf16x8*)&Ws[(wc + nt * 16 + p) * 32 + q * 8];
        #pragma unroll
        for (int mt = 0; mt < 4; mt++)
            #pragma unroll
            for (int nt = 0; nt < 4; nt++)
                acc[mt][nt] = __builtin_amdgcn_mfma_f32_16x16x32_bf16(afr[mt], wfr[nt], acc[mt][nt], 0, 0, 0);
    }

    float* Sz = S + (size_t)z * 65536;
    #pragma unroll
    for (int mt = 0; mt < 4; mt++)
        #pragma unroll
        for (int r = 0; r < 4; r++) {
            int grow = m0 + wr + mt * 16 + q * 4 + r;
            #pragma unroll
            for (int nt = 0; nt < 4; nt++) {
                int gcol = n0 + wc + nt * 16 + p;
                Sz[(size_t)grow * 256 + gcol] = acc[mt][nt][r];
            }
        }
}

// scale + causal mask + softmax, in place. wave per row, 2048 rows.
__global__ __launch_bounds__(256) void k_attn_soft(float* __restrict__ S)
{
    int row = blockIdx.x * 4 + (threadIdx.x >> 6);
    int l = threadIdx.x & 63;
    int qi = row & 255;
    float* sp = S + (size_t)row * 256;
    float4 v = ((const float4*)sp)[l];
    int k0 = l * 4;
    float a[4] = {v.x * SCALE, v.y * SCALE, v.z * SCALE, v.w * SCALE};
    #pragma unroll
    for (int i = 0; i < 4; i++) if (k0 + i > qi) a[i] = -1e30f;
    float m = fmaxf(fmaxf(a[0], a[1]), fmaxf(a[2], a[3]));
    for (int o = 32; o; o >>= 1) m = fmaxf(m, __shfl_xor(m, o));
    float e[4];
    #pragma unroll
    for (int i = 0; i < 4; i++) e[i] = (k0 + i <= qi) ? expf(a[i] - m) : 0.f;
    float s = e[0] + e[1] + e[2] + e[3];
    for (int o = 32; o; o >>= 1) s += __shfl_xor(s, o);
    float inv = 1.f / s;
    ((float4*)sp)[l] = make_float4(e[0]*inv, e[1]*inv, e[2]*inv, e[3]*inv);
}

// V transpose: Vt[z][d][k] = V[k][z][d]   (32x32 LDS tiles)
__global__ __launch_bounds__(256) void k_vt(
    const float* __restrict__ qkv, float* __restrict__ Vt)
{
    __shared__ float tile[32][33];
    int z = blockIdx.z, b = z >> 1, h = z & 1;
    int d0 = blockIdx.x * 32, k0 = blockIdx.y * 32;
    int c = threadIdx.x & 31, r0 = threadIdx.x >> 5;
    size_t boff = (size_t)b * 768 + 512 + h * 128;
    for (int r = r0; r < 32; r += 8)
        tile[r][c] = qkv[(size_t)(k0 + r) * 3072 + boff + d0 + c];
    __syncthreads();
    for (int r = r0; r < 32; r += 8)
        Vt[(size_t)z * 32768 + (size_t)(d0 + r) * 256 + k0 + c] = tile[c][r];
}

// O = P @ V : M=256 (q), N=128 (dh), K=256 (keys). Writes node-activation layout.
__global__ __launch_bounds__(256) void k_attn_pv(
    const float* __restrict__ S, const float* __restrict__ Vt,
    float* __restrict__ out)
{
    __shared__ ushort As[128 * 32];
    __shared__ ushort Ws[128 * 32];
    int tid = threadIdx.x;
    int wave = tid >> 6, lane = tid & 63;
    int wr = (wave >> 1) * 64, wc = (wave & 1) * 64;
    int m0 = blockIdx.y * 128;
    int z = blockIdx.z, b = z >> 1, h = z & 1;
    int q = lane >> 4, p = lane & 15;

    f32x4 acc[4][4];
    #pragma unroll
    for (int i = 0; i < 4; i++)
        #pragma unroll
        for (int j = 0; j < 4; j++) acc[i][j] = (f32x4){0.f, 0.f, 0.f, 0.f};

    int srow = tid >> 1;
    int scol = (tid & 1) << 4;
    const float* Arow = S + (size_t)z * 65536 + (size_t)(m0 + srow) * 256 + scol;
    const float* Wrow = Vt + (size_t)z * 32768 + (size_t)srow * 256 + scol;   // 128 rows
    ushort* asd = &As[srow * 32 + scol];
    ushort* wsd = &Ws[srow * 32 + scol];

    for (int k0 = 0; k0 < 256; k0 += 32) {
        float av[16], wv[16];
        #pragma unroll
        for (int i = 0; i < 4; i++) {
            float4 a4 = *(const float4*)(Arow + k0 + i * 4);
            float4 w4 = *(const float4*)(Wrow + k0 + i * 4);
            av[i*4+0] = a4.x; av[i*4+1] = a4.y; av[i*4+2] = a4.z; av[i*4+3] = a4.w;
            wv[i*4+0] = w4.x; wv[i*4+1] = w4.y; wv[i*4+2] = w4.z; wv[i*4+3] = w4.w;
        }
        unsigned au[8], wu[8];
        #pragma unroll
        for (int i = 0; i < 8; i++) {
            au[i] = (unsigned)f2b(av[2*i]) | ((unsigned)f2b(av[2*i+1]) << 16);
            wu[i] = (unsigned)f2b(wv[2*i]) | ((unsigned)f2b(wv[2*i+1]) << 16);
        }
        __syncthreads();
        ((uint4*)asd)[0] = make_uint4(au[0], au[1], au[2], au[3]);
        ((uint4*)(asd + 8))[0] = make_uint4(au[4], au[5], au[6], au[7]);
        ((uint4*)wsd)[0] = make_uint4(wu[0], wu[1], wu[2], wu[3]);
        ((uint4*)(wsd + 8))[0] = make_uint4(wu[4], wu[5], wu[6], wu[7]);
        __syncthreads();

        bf16x8 afr[4], wfr[4];
        #pragma unroll
        for (int mt = 0; mt < 4; mt++)
            afr[mt] = *(const bf16x8*)&As[(wr + mt * 16 + p) * 32 + q * 8];
        #pragma unroll
        for (int nt = 0; nt < 4; nt++)
            wfr[nt] = *(const bf16x8*)&Ws[(wc + nt * 16 + p) * 32 + q * 8];
        #pragma unroll
        for (int mt = 0; mt < 4; mt++)
            #pragma unroll
            for (int nt = 0; nt < 4; nt++)
                acc[mt][nt] = __builtin_amdgcn_mfma_f32_16x16x32_bf16(afr[mt], wfr[nt], acc[mt][nt], 0, 0, 0);
    }

    #pragma unroll
    for (int mt = 0; mt < 4; mt++)
        #pragma unroll
        for (int r = 0; r < 4; r++) {
            int grow = m0 + wr + mt * 16 + q * 4 + r;    // query index
            #pragma unroll
            for (int nt = 0; nt < 4; nt++) {
                int dh = wc + nt * 16 + p;               // 0..127
                out[(size_t)grow * 1024 + (size_t)b * 256 + h * 128 + dh] = acc[mt][nt][r];
            }
        }
}

// ---------------- generic fp32 GEMM (small/odd shapes only) ----------------

__global__ __launch_bounds__(256) void k_gemm(
    const float* __restrict__ A, const float* __restrict__ W,
    const float* __restrict__ bias, float* __restrict__ C,
    int M, int N, int K, int relu)
{
    __shared__ __align__(16) float As[16][68];
    __shared__ __align__(16) float Ws[16][68];
    int tx = threadIdx.x, ty = threadIdx.y;
    int tid = ty * 16 + tx;
    int m0 = blockIdx.y * 64, n0 = blockIdx.x * 64;
    float acc[4][4] = {{0.f}};
    int r  = tid >> 2;
    int kk = (tid & 3) << 2;
    bool k4 = ((K & 3) == 0);
    for (int k0 = 0; k0 < K; k0 += 16) {
        float4 av = make_float4(0.f, 0.f, 0.f, 0.f);
        float4 wv = make_float4(0.f, 0.f, 0.f, 0.f);
        int gm = m0 + r, gk = k0 + kk;
        if (gm < M) {
            if (k4 && gk + 4 <= K) av = *(const float4*)(A + (size_t)gm * K + gk);
            else {
                float tv[4];
                for (int i = 0; i < 4; i++) tv[i] = (gk + i < K) ? A[(size_t)gm * K + gk + i] : 0.f;
                av = make_float4(tv[0], tv[1], tv[2], tv[3]);
            }
        }
        int gn = n0 + r;
        if (gn < N) {
            if (k4 && gk + 4 <= K) wv = *(const float4*)(W + (size_t)gn * K + gk);
            else {
                float tv[4];
                for (int i = 0; i < 4; i++) tv[i] = (gk + i < K) ? W[(size_t)gn * K + gk + i] : 0.f;
                wv = make_float4(tv[0], tv[1], tv[2], tv[3]);
            }
        }
        As[kk + 0][r] = av.x; As[kk + 1][r] = av.y; As[kk + 2][r] = av.z; As[kk + 3][r] = av.w;
        Ws[kk + 0][r] = wv.x; Ws[kk + 1][r] = wv.y; Ws[kk + 2][r] = wv.z; Ws[kk + 3][r] = wv.w;
        __syncthreads();
        #pragma unroll
        for (int k = 0; k < 16; k++) {
            float4 a4 = *(const float4*)&As[k][ty << 2];
            float4 b4 = *(const float4*)&Ws[k][tx << 2];
            float a[4] = {a4.x, a4.y, a4.z, a4.w};
            float b[4] = {b4.x, b4.y, b4.z, b4.w};
            #pragma unroll
            for (int i = 0; i < 4; i++)
                #pragma unroll
                for (int j = 0; j < 4; j++)
                    acc[i][j] = fmaf(a[i], b[j], acc[i][j]);
        }
        __syncthreads();
    }
    #pragma unroll
    for (int i = 0; i < 4; i++) {
        int gm = m0 + (ty << 2) + i;
        if (gm >= M) continue;
        #pragma unroll
        for (int j = 0; j < 4; j++) {
            int gn = n0 + (tx << 2) + j;
            if (gn >= N) continue;
            float v = acc[i][j] + bias[gn];
            if (relu) v = fmaxf(v, 0.f);
            C[(size_t)gm * N + gn] = v;
        }
    }
}

// ---------------- residual + LayerNorm ----------------

__global__ __launch_bounds__(256) void k_add_ln(
    const float* __restrict__ x, const float* __restrict__ delta,
    const float* __restrict__ g, const float* __restrict__ bta,
    float* __restrict__ out, int M, int mode)
{
    int row = blockIdx.x * 4 + (threadIdx.x >> 6);
    int t = threadIdx.x & 63;
    if (row >= M) return;
    float4 v = ((const float4*)(x + (size_t)row * HH))[t];
    if (mode == 0) {
        float4 d = ((const float4*)(delta + (size_t)row * HH))[t];
        v.x += d.x; v.y += d.y; v.z += d.z; v.w += d.w;
    } else if (mode == 1) {
        float4 d = ((const float4*)(delta + (size_t)(row & 3) * HH))[t];
        v.x += d.x; v.y += d.y; v.z += d.z; v.w += d.w;
    }
    float s = v.x + v.y + v.z + v.w;
    for (int o = 32; o; o >>= 1) s += __shfl_down(s, o);
    float mean = __shfl(s, 0) * (1.f / 256.f);
    float cx = v.x - mean, cy = v.y - mean, cz = v.z - mean, cw = v.w - mean;
    float q = cx * cx + cy * cy + cz * cz + cw * cw;
    for (int o = 32; o; o >>= 1) q += __shfl_down(q, o);
    float rstd = rsqrtf(__shfl(q, 0) * (1.f / 256.f) + 1e-5f);
    float4 gg = ((const float4*)g)[t];
    float4 bb = ((const float4*)bta)[t];
    float4 o4;
    o4.x = cx * rstd * gg.x + bb.x;
    o4.y = cy * rstd * gg.y + bb.y;
    o4.z = cz * rstd * gg.z + bb.z;
    o4.w = cw * rstd * gg.w + bb.w;
    ((float4*)(out + (size_t)row * HH))[t] = o4;
}

// ---------------- BatchNorm partial sums ----------------

__global__ __launch_bounds__(256) void k_bn_part(const float* __restrict__ x, float* __restrict__ sums) {
    int t = threadIdx.x;
    int r0 = blockIdx.x * 16;
    float s = 0.f, s2 = 0.f;
    for (int r = r0; r < r0 + 16; r++) {
        float v = x[(size_t)r * 256 + t];
        s += v; s2 += v * v;
    }
    atomicAdd(&sums[t], s);
    atomicAdd(&sums[256 + t], s2);
}

// ---------------- BN-finalize + SELU + positional encoding ----------------

__global__ __launch_bounds__(256) void k_bn_selu_pe(
    const float* __restrict__ x0, const float* __restrict__ sums,
    const float* __restrict__ g, const float* __restrict__ b,
    const int* __restrict__ atom_i, float* __restrict__ out)
{
    int row = blockIdx.x, t = threadIdx.x;
    float m = sums[t] * (1.f / 1024.f);
    float var = sums[256 + t] * (1.f / 1024.f) - m * m;
    float rstd = rsqrtf(var + 1e-5f);
    float v = x0[(size_t)row * 256 + t];
    v = (v - m) * rstd * g[t] + b[t];
    const float SC = 1.0507009873554805f, AL = 1.6732632423543772f;
    v = SC * (v > 0.f ? v : AL * expm1f(v));
    float pos = (float)atom_i[row];
    float freq = expf(-(float)t * (9.210340371976184f / 256.f));
    float ang = pos * freq;
    float pe = (t & 1) ? cosf(ang) : sinf(ang);
    out[(size_t)row * 256 + t] = v + pe;
}

// ---------------- edge group self-attention ----------------

__global__ __launch_bounds__(256) void k_edge_self_attn(
    const float* __restrict__ qkv, float* __restrict__ out)
{
    int g = blockIdx.x + 1;
    int b = blockIdx.y;
    int gs = min(g, 12);
    int base = (g <= 13) ? g * (g - 1) / 2 : 78 + (g - 13) * 12;
    int h = threadIdx.x >> 7;
    int t = threadIdx.x & 127;
    __shared__ float qs[2][12][128], ks[2][12][128], vs[2][12][128];
    __shared__ float ps[2][12][12];
    for (int i = 0; i < gs; i++) {
        size_t row = ((size_t)(base + i) * BB + b) * 768 + h * 128 + t;
        qs[h][i][t] = qkv[row];
        ks[h][i][t] = qkv[row + 256];
        vs[h][i][t] = qkv[row + 512];
    }
    __syncthreads();
    for (int p = t; p < gs * gs; p += 128) {
        int i = p / gs, j = p - i * gs;
        float acc = 0.f;
        for (int d = 0; d < 128; d++) acc = fmaf(qs[h][i][d], ks[h][j][d], acc);
        ps[h][i][j] = acc * SCALE;
    }
    __syncthreads();
    if (t < gs) {
        float m = -1e30f;
        for (int j = 0; j < gs; j++) m = fmaxf(m, ps[h][t][j]);
        float e[12]; float s = 0.f;
        for (int j = 0; j < gs; j++) { e[j] = expf(ps[h][t][j] - m); s += e[j]; }
        float inv = 1.f / s;
        for (int j = 0; j < gs; j++) ps[h][t][j] = e[j] * inv;
    }
    __syncthreads();
    for (int i = 0; i < gs; i++) {
        float acc = 0.f;
        for (int j = 0; j < gs; j++) acc = fmaf(ps[h][i][j], vs[h][j][t], acc);
        out[((size_t)(base + i) * BB + b) * 256 + h * 128 + t] = acc;
    }
}

// ---------------- edge 2-key cross-attention ----------------

__global__ __launch_bounds__(128) void k_edge_cross_attn(
    const float* __restrict__ Q, const float* __restrict__ KV,
    const int* __restrict__ grp, float* __restrict__ out)
{
    int e = blockIdx.x, b = blockIdx.y;
    int h = threadIdx.x >> 6, l = threadIdx.x & 63;
    int g = grp[e];
    size_t qrow = ((size_t)e * BB + b) * 256 + h * 128;
    float qa = Q[qrow + l], qb = Q[qrow + 64 + l];
    size_t k0r = (size_t)b * 512 + h * 128;
    size_t k1r = ((size_t)(g + 1) * BB + b) * 512 + h * 128;
    float p0 = qa * KV[k0r + l] + qb * KV[k0r + 64 + l];
    float p1 = qa * KV[k1r + l] + qb * KV[k1r + 64 + l];
    for (int o = 32; o; o >>= 1) { p0 += __shfl_down(p0, o); p1 += __shfl_down(p1, o); }
    p0 = __shfl(p0, 0) * SCALE;
    p1 = __shfl(p1, 0) * SCALE;
    float m = fmaxf(p0, p1);
    float e0 = expf(p0 - m), e1 = expf(p1 - m);
    float inv = 1.f / (e0 + e1);
    e0 *= inv; e1 *= inv;
    out[qrow + l]      = e0 * KV[k0r + 256 + l]      + e1 * KV[k1r + 256 + l];
    out[qrow + 64 + l] = e0 * KV[k0r + 256 + 64 + l] + e1 * KV[k1r + 256 + 64 + l];
}

// ---------------- gathers ----------------

__global__ __launch_bounds__(256) void k_gather(
    const float* __restrict__ src, const int* __restrict__ idxt, float* __restrict__ dst)
{
    int r = blockIdx.x, t = threadIdx.x;
    int e = r >> 2, b = r & 3;
    dst[(size_t)r * 256 + t] = src[((size_t)idxt[e] * 4 + b) * 256 + t];
}

__global__ __launch_bounds__(256) void k_build_mem(
    const float* __restrict__ z, const float* __restrict__ nemb, float* __restrict__ mem)
{
    int r = blockIdx.x, t = threadIdx.x;
    int m = r >> 2, b = r & 3;
    mem[(size_t)r * 256 + t] = (m == 0) ? z[(size_t)b * 256 + t]
                                        : nemb[((size_t)(m - 1) * 4 + b) * 256 + t];
}

// ---------------- fused cross-entropy ----------------

__global__ __launch_bounds__(256) void k_ce_node(
    const float* __restrict__ emb,
    const float* __restrict__ w0, const float* __restrict__ b0,
    const float* __restrict__ w1, const float* __restrict__ b1,
    const float* __restrict__ w2, const float* __restrict__ b2,
    const int* __restrict__ y, int M, float invM, float* __restrict__ lossOut)
{
    int wave = threadIdx.x >> 6, lane = threadIdx.x & 63;
    int wid = blockIdx.x * 4 + wave;
    float local = 0.f;
    for (int r = wid; r < M; r += gridDim.x * 4) {
        float4 x = ((const float4*)(emb + (size_t)r * 256))[lane];
        float acc[54];
        #pragma unroll
        for (int c = 0; c < 40; c++) {
            float4 wv = ((const float4*)(w0 + (size_t)c * 256))[lane];
            acc[c] = x.x * wv.x + x.y * wv.y + x.z * wv.z + x.w * wv.w;
        }
        #pragma unroll
        for (int c = 0; c < 8; c++) {
            float4 wv = ((const float4*)(w1 + (size_t)c * 256))[lane];
            acc[40 + c] = x.x * wv.x + x.y * wv.y + x.z * wv.z + x.w * wv.w;
        }
        #pragma unroll
        for (int c = 0; c < 6; c++) {
            float4 wv = ((const float4*)(w2 + (size_t)c * 256))[lane];
            acc[48 + c] = x.x * wv.x + x.y * wv.y + x.z * wv.z + x.w * wv.w;
        }
        #pragma unroll
        for (int c = 0; c < 54; c++)
            for (int o = 32; o; o >>= 1) acc[c] += __shfl_down(acc[c], o);
        if (lane == 0) {
            int y0 = y[(size_t)r * 3 + 0], y1 = y[(size_t)r * 3 + 1], y2 = y[(size_t)r * 3 + 2];
            float m0 = -1e30f, m1 = -1e30f, m2 = -1e30f;
            float lg[54];
            for (int c = 0; c < 40; c++) { lg[c] = acc[c] + b0[c]; m0 = fmaxf(m0, lg[c]); }
            for (int c = 0; c < 8; c++)  { lg[40 + c] = acc[40 + c] + b1[c]; m1 = fmaxf(m1, lg[40 + c]); }
            for (int c = 0; c < 6; c++)  { lg[48 + c] = acc[48 + c] + b2[c]; m2 = fmaxf(m2, lg[48 + c]); }
            float s0 = 0.f, s1 = 0.f, s2 = 0.f;
            for (int c = 0; c < 40; c++) s0 += expf(lg[c] - m0);
            for (int c = 0; c < 8; c++)  s1 += expf(lg[40 + c] - m1);
            for (int c = 0; c < 6; c++)  s2 += expf(lg[48 + c] - m2);
            local += (m0 + logf(s0) - lg[y0]) + (m1 + logf(s1) - lg[40 + y1]) + (m2 + logf(s2) - lg[48 + y2]);
        }
    }
    __shared__ float ls[4];
    if (lane == 0) ls[wave] = local;
    __syncthreads();
    if (threadIdx.x == 0)
        atomicAdd(lossOut, (ls[0] + ls[1] + ls[2] + ls[3]) * invM);
}

__global__ __launch_bounds__(256) void k_ce_edge(
    const float* __restrict__ emb,
    const float* __restrict__ w0, const float* __restrict__ b0,
    const float* __restrict__ w1, const float* __restrict__ b1,
    const int* __restrict__ y, int M, float invM, float* __restrict__ lossOut)
{
    int wave = threadIdx.x >> 6, lane = threadIdx.x & 63;
    int wid = blockIdx.x * 4 + wave;
    float local = 0.f;
    for (int r = wid; r < M; r += gridDim.x * 4) {
        float4 x = ((const float4*)(emb + (size_t)r * 256))[lane];
        float acc[9];
        #pragma unroll
        for (int c = 0; c < 5; c++) {
            float4 wv = ((const float4*)(w0 + (size_t)c * 256))[lane];
            acc[c] = x.x * wv.x + x.y * wv.y + x.z * wv.z + x.w * wv.w;
        }
        #pragma unroll
        for (int c = 0; c < 4; c++) {
            float4 wv = ((const float4*)(w1 + (size_t)c * 256))[lane];
            acc[5 + c] = x.x * wv.x + x.y * wv.y + x.z * wv.z + x.w * wv.w;
        }
        #pragma unroll
        for (int c = 0; c < 9; c++)
            for (int o = 32; o; o >>= 1) acc[c] += __shfl_down(acc[c], o);
        if (lane == 0) {
            int y0 = y[(size_t)r * 2 + 0], y1 = y[(size_t)r * 2 + 1];
            float lg[9];
            float m0 = -1e30f, m1 = -1e30f;
            for (int c = 0; c < 5; c++) { lg[c] = acc[c] + b0[c]; m0 = fmaxf(m0, lg[c]); }
            for (int c = 0; c < 4; c++) { lg[5 + c] = acc[5 + c] + b1[c]; m1 = fmaxf(m1, lg[5 + c]); }
            float s0 = 0.f, s1 = 0.f;
            for (int c = 0; c < 5; c++) s0 += expf(lg[c] - m0);
            for (int c = 0; c < 4; c++) s1 += expf(lg[5 + c] - m1);
            local += (m0 + logf(s0) - lg[y0]) + (m1 + logf(s1) - lg[5 + y1]);
        }
    }
    __shared__ float ls[4];
    if (lane == 0) ls[wave] = local;
    __syncthreads();
    if (threadIdx.x == 0)
        atomicAdd(lossOut, (ls[0] + ls[1] + ls[2] + ls[3]) * invM);
}

// ---------------- host ----------------

extern "C" void kernel_launch(void* const* d_in, const int* in_sizes, int n_in,
                              void* d_out, int out_size, void* d_ws, size_t ws_size,
                              hipStream_t stream)
{
    (void)in_sizes; (void)n_in; (void)out_size; (void)ws_size;
    const float* z        = (const float*)d_in[0];
    const int*   atom_i   = (const int*)d_in[1];
    const float* atom_x   = (const float*)d_in[2];
    const int*   atom_y   = (const int*)d_in[3];
    const int*   bond_y   = (const int*)d_in[4];
    const float* Wp       = (const float*)d_in[5];
    const float* bp       = (const float*)d_in[6];
    const float* bn_g     = (const float*)d_in[7];
    const float* bn_b     = (const float*)d_in[8];
    const float* nd_qkv_w = (const float*)d_in[9];
    const float* nd_qkv_b = (const float*)d_in[10];
    const float* nd_so_w  = (const float*)d_in[11];
    const float* nd_so_b  = (const float*)d_in[12];
    const float* nd_cqkv_w= (const float*)d_in[13];
    const float* nd_cqkv_b= (const float*)d_in[14];
    const float* nd_co_w  = (const float*)d_in[15];
    const float* nd_co_b  = (const float*)d_in[16];
    const float* nd_ff1_w = (const float*)d_in[17];
    const float* nd_ff1_b = (const float*)d_in[18];
    const float* nd_ff2_w = (const float*)d_in[19];
    const float* nd_ff2_b = (const float*)d_in[20];
    const float* nd_ln_g  = (const float*)d_in[21];
    const float* nd_ln_b  = (const float*)d_in[22];
    const float* nd_fn_g  = (const float*)d_in[23];
    const float* nd_fn_b  = (const float*)d_in[24];
    const float* ed_qkv_w = (const float*)d_in[25];
    const float* ed_qkv_b = (const float*)d_in[26];
    const float* ed_so_w  = (const float*)d_in[27];
    const float* ed_so_b  = (const float*)d_in[28];
    const float* ed_cqkv_w= (const float*)d_in[29];
    const float* ed_cqkv_b= (const float*)d_in[30];
    const float* ed_co_w  = (const float*)d_in[31];
    const float* ed_co_b  = (const float*)d_in[32];
    const float* ed_ff1_w = (const float*)d_in[33];
    const float* ed_ff1_b = (const float*)d_in[34];
    const float* ed_ff2_w = (const float*)d_in[35];
    const float* ed_ff2_b = (const float*)d_in[36];
    const float* ed_ln_g  = (const float*)d_in[37];
    const float* ed_ln_b  = (const float*)d_in[38];
    const float* ed_fn_g  = (const float*)d_in[39];
    const float* ed_fn_b  = (const float*)d_in[40];
    const float* nc0_w = (const float*)d_in[41]; const float* nc0_b = (const float*)d_in[42];
    const float* nc1_w = (const float*)d_in[43]; const float* nc1_b = (const float*)d_in[44];
    const float* nc2_w = (const float*)d_in[45]; const float* nc2_b = (const float*)d_in[46];
    const float* ec0_w = (const float*)d_in[47]; const float* ec0_b = (const float*)d_in[48];
    const float* ec1_w = (const float*)d_in[49]; const float* ec1_b = (const float*)d_in[50];

    float* out = (float*)d_out;

    char* wsb = (char*)d_ws;
    size_t off = 0;
    auto alloc = [&](size_t nfloats) -> float* {
        float* p = (float*)(wsb + off);
        off += ((nfloats * 4 + 255) / 256) * 256;
        return p;
    };
    float* x0   = alloc(1024 * 256);
    float* tgt  = alloc(1024 * 256);
    float* nqkv = alloc(1024 * 768);
    float* t1   = alloc(1024 * 256);
    float* t2   = alloc(1024 * 256);
    float* nemb = alloc(1024 * 256);
    float* bnsums = alloc(512);
    float* crT  = alloc(4 * 256);
    float* crO  = alloc(4 * 256);
    float* memb = alloc(1028 * 256);
    float* KV   = alloc(1028 * 512);
    float* Sbuf = alloc(8 * 256 * 256);
    float* Vt   = alloc(8 * 128 * 256);
    float* etgt = alloc((size_t)LEB * 256);
    float* eqkv = alloc((size_t)LEB * 768);
    float* et1  = alloc((size_t)LEB * 256);
    float* et2  = alloc((size_t)LEB * 256);
    int* grp  = (int*)(wsb + off); off += ((LE * 4 + 255) / 256) * 256;
    int* idxt = (int*)(wsb + off); off += ((LE * 4 + 255) / 256) * 256;

    dim3 blk(16, 16);
    auto gemm = [&](const float* A, const float* W, const float* bi, float* C,
                    int M, int N, int K, int relu) {
        dim3 grid((N + 63) / 64, (M + 63) / 64);
        k_gemm<<<grid, blk, 0, stream>>>(A, W, bi, C, M, N, K, relu);
    };
    auto gemm_bf = [&](const float* A, const float* W, const float* bi, float* C,
                       int M, int N, int K, int relu) {
        dim3 grid(N / 128, (M + 127) / 128);
        k_gemm_mfma<<<grid, 256, 0, stream>>>(A, W, bi, C, M, N, K, relu);
    };

    k_zero<<<1, 256, 0, stream>>>(out, 1);
    k_zero<<<2, 256, 0, stream>>>(bnsums, 512);
    k_init_tables<<<12, 256, 0, stream>>>(grp, idxt);

    // node input: projection + BN(training stats) + SELU + positional encoding
    gemm(atom_x, Wp, bp, x0, 1024, 256, 54, 0);
    k_bn_part<<<64, 256, 0, stream>>>(x0, bnsums);
    k_bn_selu_pe<<<1024, 256, 0, stream>>>(x0, bnsums, bn_g, bn_b, atom_i, tgt);

    // node decoder: 2 layers
    for (int l = 0; l < 2; l++) {
        gemm_bf(tgt, nd_qkv_w + (size_t)l * 768 * 256, nd_qkv_b + l * 768, nqkv, 1024, 768, 256, 0);
        // MFMA attention: S = QK^T, softmax, O = P V
        k_vt<<<dim3(4, 8, 8), 256, 0, stream>>>(nqkv, Vt);
        k_attn_qk<<<dim3(2, 2, 8), 256, 0, stream>>>(nqkv, Sbuf);
        k_attn_soft<<<512, 256, 0, stream>>>(Sbuf);
        k_attn_pv<<<dim3(1, 2, 8), 256, 0, stream>>>(Sbuf, Vt, t1);
        gemm_bf(t1, nd_so_w + (size_t)l * 65536, nd_so_b + l * 256, t2, 1024, 256, 256, 0);
        k_add_ln<<<256, 256, 0, stream>>>(tgt, t2, nd_ln_g + (l * 3 + 0) * 256, nd_ln_b + (l * 3 + 0) * 256, tgt, 1024, 0);
        gemm(z,   nd_cqkv_w + (size_t)l * 768 * 256 + 512 * 256, nd_cqkv_b + l * 768 + 512, crT, 4, 256, 256, 0);
        gemm(crT, nd_co_w + (size_t)l * 65536, nd_co_b + l * 256, crO, 4, 256, 256, 0);
        k_add_ln<<<256, 256, 0, stream>>>(tgt, crO, nd_ln_g + (l * 3 + 1) * 256, nd_ln_b + (l * 3 + 1) * 256, tgt, 1024, 1);
        gemm_bf(tgt, nd_ff1_w + (size_t)l * 65536, nd_ff1_b + l * 256, t1, 1024, 256, 256, 1);
        gemm_bf(t1,  nd_ff2_w + (size_t)l * 65536, nd_ff2_b + l * 256, t2, 1024, 256, 256, 0);
        k_add_ln<<<256, 256, 0, stream>>>(tgt, t2, nd_ln_g + (l * 3 + 2) * 256, nd_ln_b + (l * 3 + 2) * 256, tgt, 1024, 0);
    }
    k_add_ln<<<256, 256, 0, stream>>>(tgt, nullptr, nd_fn_g, nd_fn_b, nemb, 1024, 2);

    // node losses
    k_ce_node<<<128, 256, 0, stream>>>(nemb, nc0_w, nc0_b, nc1_w, nc1_b, nc2_w, nc2_b,
                                       atom_y, 1024, 1.f / 1024.f, out);

    // edge path
    k_gather<<<LEB, 256, 0, stream>>>(nemb, idxt, etgt);
    k_build_mem<<<1028, 256, 0, stream>>>(z, nemb, memb);
    gemm_bf(memb, ed_cqkv_w + 256 * 256, ed_cqkv_b + 256, KV, 1028, 512, 256, 0);

    gemm_bf(etgt, ed_qkv_w, ed_qkv_b, eqkv, LEB, 768, 256, 0);
    k_edge_self_attn<<<dim3(255, 4), 256, 0, stream>>>(eqkv, et1);
    gemm_bf(et1, ed_so_w, ed_so_b, et2, LEB, 256, 256, 0);
    k_add_ln<<<LEB / 4, 256, 0, stream>>>(etgt, et2, ed_ln_g + 0, ed_ln_b + 0, etgt, LEB, 0);

    gemm_bf(etgt, ed_cqkv_w, ed_cqkv_b, eqkv, LEB, 256, 256, 0);
    k_edge_cross_attn<<<dim3(LE, 4), 128, 0, stream>>>(eqkv, KV, grp, et1);
    gemm_bf(et1, ed_co_w, ed_co_b, et2, LEB, 256, 256, 0);
    k_add_ln<<<LEB / 4, 256, 0, stream>>>(etgt, et2, ed_ln_g + 256, ed_ln_b + 256, etgt, LEB, 0);

    gemm_bf(etgt, ed_ff1_w, ed_ff1_b, et1, LEB, 256, 256, 1);
    gemm_bf(et1,  ed_ff2_w, ed_ff2_b, et2, LEB, 256, 256, 0);
    k_add_ln<<<LEB / 4, 256, 0, stream>>>(etgt, et2, ed_ln_g + 512, ed_ln_b + 512, etgt, LEB, 0);
    k_add_ln<<<LEB / 4, 256, 0, stream>>>(etgt, nullptr, ed_fn_g, ed_fn_b, etgt, LEB, 2);

    // edge losses
    k_ce_edge<<<512, 256, 0, stream>>>(etgt, ec0_w, ec0_b, ec1_w, ec1_b,
                                       bond_y, LEB, 1.f / (float)LEB, out);
}